// Round 12
// baseline (1263.664 us; speedup 1.0000x reference)
//
#include <hip/hip_runtime.h>
#include <stdint.h>

typedef unsigned long long u64;
typedef unsigned int u32;

static constexpr u64 KEMPTY = ~0ull;
static constexpr int PROBE_CAP = 32768;
static constexpr u32 BINS  = 4096;
static constexpr u32 CHUNK = 4096;
static constexpr u32 SPLIT = 2048;

// ---- tier-2 pass path (4551 < U <= THRESH) ----
static constexpr u32 RPP    = 960;
static constexpr u32 TOTAL_B= 512;
static constexpr u32 PMAX   = 24;
static constexpr u32 THRESH = RPP*PMAX;       // 23040

// ---- tier-1 single-pass channel-split path (U <= U2CAP) ----
static constexpr u32 U2CAP = 4551;            // 4551*9*4 = 163836 B <= 160 KiB LDS
static constexpr u32 LDS2B = U2CAP*9*4;
static constexpr u32 S2    = 128;             // point subranges; grid = 2*S2 = 256 blocks

static __device__ __forceinline__ u64 mix64(u64 x){
  x ^= x >> 30; x *= 0xbf58476d1ce4e5b9ull;
  x ^= x >> 27; x *= 0x94d049bb133111ebull;
  x ^= x >> 31; return x;
}

static __device__ __forceinline__ long long lookup_slot(const u64* __restrict__ tk, u32 cmask, u64 code){
  u32 h = (u32)mix64(code) & cmask;
#pragma unroll 1
  for(int p=0;p<PROBE_CAP;p++){
    u64 cur = tk[h];
    if(cur==code) return (long long)h;
    if(cur==KEMPTY) return -1;
    h=(h+1)&cmask;
  }
  return -1;
}

static __device__ __forceinline__ void atomAddF(float* p, float v){
#if defined(__gfx90a__) || defined(__gfx940__) || defined(__gfx941__) || defined(__gfx942__) || defined(__gfx950__)
  unsafeAtomicAdd(p, v);
#else
  atomicAdd(p, v);
#endif
}

static __device__ __forceinline__ void lds_add(float* p, float v){
  __hip_atomic_fetch_add(p, v, __ATOMIC_RELAXED, __HIP_MEMORY_SCOPE_WORKGROUP);
}
static __device__ __forceinline__ void lds_addu(u32* p, u32 v){
  __hip_atomic_fetch_add(p, v, __ATOMIC_RELAXED, __HIP_MEMORY_SCOPE_WORKGROUP);
}
static __device__ __forceinline__ u32 lds_addu_rtn(u32* p, u32 v){
  return __hip_atomic_fetch_add(p, v, __ATOMIC_RELAXED, __HIP_MEMORY_SCOPE_WORKGROUP);
}

static __device__ __forceinline__ void row_load(const float* __restrict__ p, float* o){
  const float4* q=(const float4*)p;
#pragma unroll
  for(int i=0;i<4;i++){ float4 v=q[i]; o[4*i]=v.x; o[4*i+1]=v.y; o[4*i+2]=v.z; o[4*i+3]=v.w; }
}
static __device__ __forceinline__ void row_store(float* __restrict__ p, const float* o){
  float4* q=(float4*)p;
#pragma unroll
  for(int i=0;i<4;i++) q[i]=make_float4(o[4*i],o[4*i+1],o[4*i+2],o[4*i+3]);
}

// ---------------- kernel 1: elevate/rank/bary + table insert; stores SLOT in inv ----------------
__global__ void __launch_bounds__(256)
k_setup(const float* __restrict__ feat, int N,
        u64* __restrict__ tabk, u32 cmask,
        u32* __restrict__ inv_slot, float* __restrict__ bary)
{
#pragma clang fp contract(off)
  int n = blockIdx.x*256 + threadIdx.x;
  if(n>=N) return;

  const float s0=3.4641016151377544f, s1=2.0f, s2=1.4142135623730951f,
              s3=1.0954451150103321f, s4=0.8944271909999159f;
  float c[5];
  c[0]=feat[n*5+0]*s0; c[1]=feat[n*5+1]*s1; c[2]=feat[n*5+2]*s2;
  c[3]=feat[n*5+3]*s3; c[4]=feat[n*5+4]*s4;

  float sfx[6]; sfx[5]=0.f;
#pragma unroll
  for(int i=4;i>=0;i--) sfx[i]=sfx[i+1]+c[i];
  float el[6];
  el[0]=sfx[0];
#pragma unroll
  for(int i=1;i<6;i++) el[i]=sfx[i]-(float)i*c[i-1];

  const float down=1.0f/6.0f;
  float rd[6], rem0[6], rdsum=0.f;
#pragma unroll
  for(int i=0;i<6;i++){ rd[i]=rintf(el[i]*down); rem0[i]=rd[i]*6.0f; rdsum+=rd[i]; }
  int sumi=(int)rdsum;

  float diff[6];
#pragma unroll
  for(int i=0;i<6;i++) diff[i]=(el[i]-rem0[i])*down;

  int rank[6];
#pragma unroll
  for(int i=0;i<6;i++){
    int r=0;
#pragma unroll
    for(int j=0;j<6;j++)
      r += (diff[j]>diff[i]) || (diff[j]==diff[i] && j<i);
    rank[i]=r+sumi;
  }
  int rem0i[6];
#pragma unroll
  for(int i=0;i<6;i++){
    rem0i[i]=(int)rem0[i];
    int sh=(rank[i]<0)-(rank[i]>5);
    rank[i]+=6*sh; rem0i[i]+=6*sh;
  }

  float b[7]={0.f,0.f,0.f,0.f,0.f,0.f,0.f};
#pragma unroll
  for(int i=0;i<6;i++){
    float t=(el[i]-(float)rem0i[i])*down;
    int k0=5-rank[i]; if(k0>=0&&k0<7) b[k0]+=t;
  }
#pragma unroll
  for(int i=0;i<6;i++){
    float t=(el[i]-(float)rem0i[i])*down;
    int k1=6-rank[i]; if(k1>=0&&k1<7) b[k1]-=t;
  }
  bary[(size_t)n*6+0]=(b[0]+1.0f)+b[6];
#pragma unroll
  for(int r=1;r<6;r++) bary[(size_t)n*6+r]=b[r];

#pragma unroll 1
  for(int r=0;r<6;r++){
    long long code=0;
#pragma unroll
    for(int i=0;i<5;i++){
      int key = rem0i[i] + ((rank[i] >= 6-r) ? (r-6) : r);
      code = code*2048 + (long long)(key+1024);
    }
    u32 h=(u32)mix64((u64)code)&cmask;
    u32 slot=0xFFFFFFFFu;
#pragma unroll 1
    for(int p=0;p<PROBE_CAP;p++){
      u64 cur=tabk[h];
      if(cur==(u64)code){ slot=h; break; }
      if(cur==KEMPTY){
        u64 old=atomicCAS((unsigned long long*)&tabk[h], KEMPTY, (u64)code);
        if(old==KEMPTY || old==(u64)code){ slot=h; break; }
      } else {
        h=(h+1)&cmask;
      }
    }
    inv_slot[(size_t)n*6+r]=slot;
  }
}

// ---------------- kernel 2: compact uids ----------------
__global__ void __launch_bounds__(256)
k_uid(const u64* __restrict__ tabk, u32 C, u32 Ucap, u32* __restrict__ tuid,
      u32* __restrict__ uidslot, u32* __restrict__ counter)
{
  u32 s=blockIdx.x*256+threadIdx.x;
  if(s>=C) return;
  if(tabk[s]==KEMPTY) return;
  u32 uid=atomicAdd(counter,1u);
  if(uid<Ucap) uidslot[uid]=s; else uid=0;
  tuid[s]=uid;
}

// ---------------- kernel 3: slot -> uid translation ----------------
__global__ void __launch_bounds__(256)
k_translate(u32* __restrict__ inv, const u32* __restrict__ tuid, size_t M)
{
  size_t i=(size_t)blockIdx.x*256+threadIdx.x;
  if(i<M) inv[i]=tuid[inv[i]];
}

// ================= TIER 1: single-pass channel-split splat (U <= U2CAP) =================
// 256 blocks (1/CU, 160KB dynamic LDS). block = (channel-half cs, point-subrange sub).
// Every entry hits its row -> every ds_add has full 64 active lanes; inv/bary
// scanned twice total (vs P=4 times); values half-rows only.
__global__ void __launch_bounds__(1024, 4)
k_saccum2(const u32* __restrict__ inv, const float* __restrict__ bary,
          const float* __restrict__ values, const u32* __restrict__ counter,
          u32 en, int N, float* __restrict__ partial2)
{
  extern __shared__ float acc2[];
  if(!en) return;
  u32 U=*counter;
  if(U>U2CAP) return;
  u32 j=blockIdx.x;
  u32 cs=j&1, sub=j>>1;
  u32 t=threadIdx.x;
  u32 tot=U*9;
  for(u32 x=t;x<tot;x+=1024) acc2[x]=0.f;
  __syncthreads();

  size_t p0=((size_t)sub*(size_t)N)/S2;
  size_t p1=((size_t)(sub+1)*(size_t)N)/S2;
  const float4* vbase=(const float4*)values;
  for(size_t i=p0+t;i<p1;i+=1024){
    const u32* ip=inv+i*6;
    const float* bp=bary+i*6;
    float4 va=vbase[i*4+cs*2];
    float4 vb=vbase[i*4+cs*2+1];
#pragma unroll
    for(int r=0;r<6;r++){
      u32 a=ip[r]*9;
      float w=bp[r];
      lds_add(&acc2[a+0], w*va.x);
      lds_add(&acc2[a+1], w*va.y);
      lds_add(&acc2[a+2], w*va.z);
      lds_add(&acc2[a+3], w*va.w);
      lds_add(&acc2[a+4], w*vb.x);
      lds_add(&acc2[a+5], w*vb.y);
      lds_add(&acc2[a+6], w*vb.z);
      lds_add(&acc2[a+7], w*vb.w);
    }
  }
  __syncthreads();
  float* dst=partial2+(size_t)j*(U2CAP*9);
  for(u32 x=t;x<tot;x+=1024) dst[x]=acc2[x];
}

// sum the S2 sub-partials of each channel-set into v0
__global__ void __launch_bounds__(256)
k_reduce2(const float* __restrict__ partial2, const u32* __restrict__ counter,
          u32 en, float* __restrict__ v0)
{
  if(!en) return;
  u32 U=*counter;
  if(U>U2CAP) return;
  u32 x=blockIdx.x*256+threadIdx.x;
  u32 csz=U*8u;
  if(x>=2u*csz) return;
  u32 cs=x/csz; u32 rem=x-cs*csz;
  u32 u=rem>>3, k=rem&7;
  const float* base=partial2+(size_t)cs*(U2CAP*9)+(size_t)u*9+k;
  float s=0.f;
  for(u32 ss=0;ss<S2;ss++) s+=base[(size_t)ss*2u*(U2CAP*9)];
  v0[(size_t)u*16+cs*8+k]=s;
}

// ================= TIER 2: pass-based stream splat (loU < U <= THRESH) =================
__global__ void __launch_bounds__(1024, 8)
k_saccum(const u32* __restrict__ inv, const float* __restrict__ bary,
         const float* __restrict__ values, const u32* __restrict__ counter,
         u32 Ucap, u32 loU, int N, float* __restrict__ partial)
{
  __shared__ float acc[RPP*17];
  u32 U=*counter; if(U>Ucap) U=Ucap;
  if(U<=loU || U>THRESH) return;
  u32 P=(U+RPP-1)/RPP;
  u32 S=TOTAL_B/P;
  u32 j=blockIdx.x;
  if(j>=P*S) return;
  u32 pass=j/S, sub=j-pass*S;
  u32 lo=pass*RPP;
  u32 t=threadIdx.x;
  for(u32 x=t;x<RPP*17;x+=1024) acc[x]=0.f;
  __syncthreads();

  size_t p0=((size_t)sub*(size_t)N)/S;
  size_t p1=((size_t)(sub+1)*(size_t)N)/S;
  for(size_t i=p0+t;i<p1;i+=1024){
    const u32* ip=inv+i*6;
    const float* bp=bary+i*6;
    u32 u[6]; float w[6];
#pragma unroll
    for(int r=0;r<6;r++){ u[r]=ip[r]-lo; w[r]=bp[r]; }
    bool any=false;
#pragma unroll
    for(int r=0;r<6;r++) any = any | (u[r]<RPP);
    if(!any) continue;
    float v[16];
    row_load(values+(size_t)i*16, v);
#pragma unroll
    for(int r=0;r<6;r++){
      if(u[r]<RPP){
        u32 a=u[r]*17; float ww=w[r];
#pragma unroll
        for(int k=0;k<16;k++) lds_add(&acc[a+k], ww*v[k]);
      }
    }
  }
  __syncthreads();
  float* dst=partial+(size_t)j*(RPP*17);
  for(u32 x=t;x<RPP*17;x+=1024) dst[x]=acc[x];
}

__global__ void __launch_bounds__(256)
k_reduce(const float* __restrict__ partial, const u32* __restrict__ counter,
         u32 Ucap, u32 loU, float* __restrict__ v0)
{
  u32 U=*counter; if(U>Ucap) U=Ucap;
  if(U<=loU || U>THRESH) return;
  u32 P=(U+RPP-1)/RPP, S=TOTAL_B/P;
  const u32 RG=RPP/16;
  u32 bid=blockIdx.x;
  u32 pass=bid/RG, rg=bid-pass*RG;
  if(pass>=P) return;
  u32 t=threadIdx.x;
  u32 r16=t>>4, k=t&15;
  u32 lrow=rg*16+r16;
  u32 gu=pass*RPP+lrow;
  const float* base=partial+((size_t)pass*S)*(RPP*17)+(size_t)lrow*17+k;
  float s=0.f;
  for(u32 ss=0;ss<S;ss++) s+=base[(size_t)ss*(RPP*17)];
  if(gu<U) v0[(size_t)gu*16+k]=s;
}

// ================= TIER 3: partition path (U > THRESH) =================
__global__ void __launch_bounds__(256)
k_hist(const u32* __restrict__ inv, const u32* __restrict__ counter,
       u32* __restrict__ hist, size_t M)
{
  if(*counter<=THRESH) return;
  __shared__ u32 h[BINS];
  u32 t=threadIdx.x, b=blockIdx.x;
#pragma unroll
  for(int j=0;j<(int)(BINS/256);j++) h[t+j*256]=0;
  __syncthreads();
  size_t base=(size_t)b*CHUNK;
#pragma unroll
  for(int j=0;j<(int)(CHUNK/256);j++){
    size_t i=base + (size_t)j*256 + t;
    if(i<M){
      u32 u=inv[i];
      lds_addu(&h[u&(BINS-1)],1u);
    }
  }
  __syncthreads();
#pragma unroll
  for(int j=0;j<(int)(BINS/256);j++){
    u32 bin=t+j*256;
    hist[(size_t)b*BINS+bin]=h[bin];
  }
}

__global__ void __launch_bounds__(256)
k_transpose(const u32* __restrict__ in, u32* __restrict__ out, u32 R, u32 C,
            const u32* __restrict__ counter)
{
  if(*counter<=THRESH) return;
  __shared__ u32 tile[32][33];
  u32 bx=blockIdx.x, by=blockIdx.y;
  u32 tx=threadIdx.x&31, ty=threadIdx.x>>5;
  u32 c0=bx*32, r0=by*32;
#pragma unroll
  for(u32 j=0;j<32;j+=8){
    u32 r=r0+ty+j, c=c0+tx;
    if(r<R && c<C) tile[ty+j][tx]=in[(size_t)r*C+c];
  }
  __syncthreads();
#pragma unroll
  for(u32 j=0;j<32;j+=8){
    u32 c=c0+ty+j, r=r0+tx;
    if(c<C && r<R) out[(size_t)c*R+r]=tile[tx][ty+j];
  }
}

__global__ void __launch_bounds__(256)
k_scan1(const u32* __restrict__ v, u32* __restrict__ bsum, const u32* __restrict__ counter)
{
  if(*counter<=THRESH) return;
  __shared__ u32 sm[256];
  u32 t=threadIdx.x, b=blockIdx.x;
  size_t base=((size_t)b*256+t)*4;
  u32 s=v[base]+v[base+1]+v[base+2]+v[base+3];
  sm[t]=s; __syncthreads();
  for(int o=128;o>0;o>>=1){ if(t<(u32)o) sm[t]+=sm[t+o]; __syncthreads(); }
  if(t==0) bsum[b]=sm[0];
}

__global__ void __launch_bounds__(256)
k_scan2(u32* __restrict__ bsum, u32 nb, const u32* __restrict__ counter)
{
  if(*counter<=THRESH) return;
  __shared__ u32 sm[256];
  u32 t=threadIdx.x;
  u32 per=(nb+255)/256;
  u32 lo=t*per, hi=lo+per; if(hi>nb) hi=nb; if(lo>nb) lo=nb;
  u32 tot=0;
  for(u32 i=lo;i<hi;i++) tot+=bsum[i];
  sm[t]=tot; __syncthreads();
  for(int o=1;o<256;o<<=1){
    u32 v=sm[t]; u32 a=(t>=(u32)o)?sm[t-o]:0u; __syncthreads();
    sm[t]=v+a; __syncthreads();
  }
  u32 run=sm[t]-tot;
  for(u32 i=lo;i<hi;i++){ u32 c=bsum[i]; bsum[i]=run; run+=c; }
}

__global__ void __launch_bounds__(256)
k_scan3(u32* __restrict__ v, const u32* __restrict__ bsum, const u32* __restrict__ counter)
{
  if(*counter<=THRESH) return;
  __shared__ u32 sm[256];
  u32 t=threadIdx.x, b=blockIdx.x;
  size_t base=((size_t)b*256+t)*4;
  u32 c[4]; u32 tot=0;
#pragma unroll
  for(int j=0;j<4;j++){ c[j]=v[base+j]; tot+=c[j]; }
  sm[t]=tot; __syncthreads();
  for(int o=1;o<256;o<<=1){
    u32 x=sm[t]; u32 a=(t>=(u32)o)?sm[t-o]:0u; __syncthreads();
    sm[t]=x+a; __syncthreads();
  }
  u32 run=bsum[b]+sm[t]-tot;
#pragma unroll
  for(int j=0;j<4;j++){ v[base+j]=run; run+=c[j]; }
}

__global__ void __launch_bounds__(256)
k_part(const u32* __restrict__ inv, const float* __restrict__ bary,
       const u32* __restrict__ histT, u32 nb,
       u32* __restrict__ skey, float* __restrict__ sw, size_t M,
       const u32* __restrict__ counter)
{
  if(*counter<=THRESH) return;
  __shared__ u32 cur[BINS];
  u32 t=threadIdx.x, b=blockIdx.x;
#pragma unroll
  for(int j=0;j<(int)(BINS/256);j++){
    u32 bin=t+j*256;
    cur[bin]=histT[(size_t)bin*nb+b];
  }
  __syncthreads();
  size_t base=(size_t)b*CHUNK;
#pragma unroll
  for(int j=0;j<(int)(CHUNK/256);j++){
    size_t i=base+(size_t)j*256+t;
    if(i<M){
      u32 u=inv[i];
      u32 pos=lds_addu_rtn(&cur[u&(BINS-1)],1u);
      skey[pos]=((u>>12)<<20)|((u32)(i/6u));
      sw[pos]=bary[i];
    }
  }
}

__global__ void __launch_bounds__(256)
k_queue(const u32* __restrict__ histT, u32 nb, size_t M,
        u32* __restrict__ q, u32* __restrict__ qn, const u32* __restrict__ counter)
{
  if(*counter<=THRESH) return;
  u32 b=blockIdx.x*256+threadIdx.x;
  if(b>=BINS) return;
  size_t s=histT[(size_t)b*nb];
  size_t e=(b+1<BINS)? (size_t)histT[(size_t)(b+1)*nb] : M;
  u32 sz=(u32)(e-s);
  if(sz==0) return;
  u32 G=(sz+SPLIT-1)/SPLIT; if(G>1023u) G=1023u;
  u32 base=atomicAdd(qn,G);
  for(u32 g=0; g<G; g++) q[base+g] = b | (g<<12) | (G<<22);
}

__global__ void __launch_bounds__(256)
k_accum(const u32* __restrict__ q, const u32* __restrict__ qn,
        const u32* __restrict__ skey, const float* __restrict__ sw,
        const float* __restrict__ values, const u32* __restrict__ histT,
        u32 nb, u32 rows, size_t M, float* __restrict__ v0)
{
  __shared__ float acc[4352];
  u32 j=blockIdx.x;
  if(j>=*qn) return;
  u32 ent=q[j];
  u32 b=ent&4095u, g=(ent>>12)&1023u, G=ent>>22;
  size_t s0=histT[(size_t)b*nb];
  size_t e0=(b+1<BINS)? (size_t)histT[(size_t)(b+1)*nb] : M;
  u32 sz=(u32)(e0-s0);
  u32 chunk=(sz+G-1)/G;
  size_t s=s0+(size_t)g*chunk;
  size_t e=s+chunk; if(e>e0) e=e0;

  u32 t=threadIdx.x;
  for(u32 x=t;x<rows*17;x+=256) acc[x]=0.f;
  __syncthreads();

  if(G==1){
    size_t base=s;
    for(; base+512<=e; base+=512){
      size_t i0=base+t, i1=base+256+t;
      u32 key0=skey[i0], key1=skey[i1];
      float w0=sw[i0], w1=sw[i1];
      float r0[16], r1[16];
      row_load(values+(size_t)(key0&0xFFFFFu)*16, r0);
      row_load(values+(size_t)(key1&0xFFFFFu)*16, r1);
      u32 a0=(key0>>20)*17, a1=(key1>>20)*17;
#pragma unroll
      for(int k=0;k<16;k++) lds_add(&acc[a0+k], w0*r0[k]);
#pragma unroll
      for(int k=0;k<16;k++) lds_add(&acc[a1+k], w1*r1[k]);
    }
    for(; base<e; base+=256){
      size_t ei=base+t;
      if(ei<e){
        u32 key=skey[ei]; float w=sw[ei];
        float r[16];
        row_load(values+(size_t)(key&0xFFFFFu)*16, r);
        u32 a=(key>>20)*17;
#pragma unroll
        for(int k=0;k<16;k++) lds_add(&acc[a+k], w*r[k]);
      }
    }
  } else {
    u32 gr=t>>4, k=t&15;
    size_t base=s;
    for(; base+128<=e; base+=128){
      u32 key[8]; float w[8]; float x[8];
#pragma unroll
      for(int u8=0;u8<8;u8++){ size_t ei=base+(size_t)u8*16+gr; key[u8]=skey[ei]; w[u8]=sw[ei]; }
#pragma unroll
      for(int u8=0;u8<8;u8++){ x[u8]=values[(size_t)(key[u8]&0xFFFFFu)*16+k]; }
#pragma unroll
      for(int u8=0;u8<8;u8++) lds_add(&acc[(key[u8]>>20)*17+k], w[u8]*x[u8]);
    }
    for(; base<e; base+=16){
      size_t ei=base+gr;
      if(ei<e){
        u32 key=skey[ei]; float w=sw[ei];
        float x=values[(size_t)(key&0xFFFFFu)*16+k];
        lds_add(&acc[(key>>20)*17+k], w*x);
      }
    }
  }
  __syncthreads();

  if(G==1){
    for(u32 x=t;x<rows*16;x+=256){
      u32 row=x>>4, kk=x&15;
      v0[(size_t)((row<<12)|b)*16+kk]=acc[row*17+kk];
    }
  } else {
    for(u32 x=t;x<rows*16;x+=256){
      u32 row=x>>4, kk=x&15;
      float a=acc[row*17+kk];
      if(a!=0.f) atomAddF(&v0[(size_t)((row<<12)|b)*16+kk], a);
    }
  }
}

// ---------------- blur ----------------
__global__ void __launch_bounds__(256)
k_blur(const u64* __restrict__ tabk, const u32* __restrict__ tuid, u32 cmask,
       const u32* __restrict__ uidslot, const u32* __restrict__ counter, u32 Ucap,
       long long delta, const float* __restrict__ vin, float* __restrict__ vout)
{
  u32 m=blockIdx.x*256+threadIdx.x;
  u32 U=*counter; if(U>Ucap) U=Ucap;
  if(m>=U) return;
  long long code=(long long)tabk[uidslot[m]];
  long long sp=lookup_slot(tabk,cmask,(u64)(code+delta));
  long long sm=lookup_slot(tabk,cmask,(u64)(code-delta));
  float acc[16];
  row_load(vin+(size_t)m*16, acc);
#pragma unroll
  for(int k=0;k<16;k++) acc[k]*=0.5f;
  if(sp>=0){
    u32 u=tuid[sp]; float t[16]; row_load(vin+(size_t)u*16,t);
#pragma unroll
    for(int k=0;k<16;k++) acc[k]+=0.25f*t[k];
  }
  if(sm>=0){
    u32 u=tuid[sm]; float t[16]; row_load(vin+(size_t)u*16,t);
#pragma unroll
    for(int k=0;k<16;k++) acc[k]+=0.25f*t[k];
  }
  row_store(vout+(size_t)m*16, acc);
}

// ---------------- slice ----------------
__global__ void __launch_bounds__(256)
k_slice(const u32* __restrict__ inv, const float* __restrict__ bary,
        const float* __restrict__ val, int N, float* __restrict__ out)
{
  int n=blockIdx.x*256+threadIdx.x;
  if(n>=N) return;
  u32 u[6]; float w[6];
#pragma unroll
  for(int r=0;r<6;r++){ u[r]=inv[(size_t)n*6+r]; w[r]=bary[(size_t)n*6+r]; }
  float t6[6][16];
#pragma unroll
  for(int r=0;r<6;r++) row_load(val+(size_t)u[r]*16, t6[r]);
  float acc[16];
#pragma unroll
  for(int k=0;k<16;k++){
    float a=w[0]*t6[0][k];
#pragma unroll
    for(int r=1;r<6;r++) a+=w[r]*t6[r][k];
    acc[k]=a;
  }
  const float alpha=0.9696969696969697f;
  float4* q=(float4*)(out+(size_t)n*16);
#pragma unroll
  for(int i=0;i<4;i++) q[i]=make_float4(alpha*acc[4*i],alpha*acc[4*i+1],alpha*acc[4*i+2],alpha*acc[4*i+3]);
}

__global__ void k_diag(float* out, float v){ out[0]=v; }

// ---------------- host ----------------
extern "C" void kernel_launch(void* const* d_in, const int* in_sizes, int n_in,
                              void* d_out, int out_size, void* d_ws, size_t ws_size,
                              hipStream_t stream)
{
  const float* feat   =(const float*)d_in[0];
  const float* values =(const float*)d_in[1];
  float* out=(float*)d_out;
  int N=in_sizes[0]/5;
  size_t M=(size_t)N*6;

  u32 nb=(u32)((M+CHUNK-1)/CHUNK);
  size_t K=(size_t)nb*BINS;
  const u32 QCAP=16384;

  // tier-1 enable: 160KB dynamic LDS must be grantable (host-side, capture-safe calls)
  u32 en=0;
  {
    int dev=0; hipGetDevice(&dev);
    int smMax=0;
    if(hipDeviceGetAttribute(&smMax, hipDeviceAttributeMaxSharedMemoryPerMultiprocessor, dev)==hipSuccess
       && (u32)smMax>=LDS2B
       && hipFuncSetAttribute((const void*)k_saccum2, hipFuncAttributeMaxDynamicSharedMemorySize, (int)LDS2B)==hipSuccess)
      en=1;
  }

  // v1 union: partition scratch OR tier-2 partials OR tier-1 partials
  size_t partial_bytes =(size_t)TOTAL_B*(RPP*17)*4;     // 33.4 MB
  size_t partial2_bytes=(size_t)(2*S2)*(size_t)(U2CAP*9)*4; // 41.9 MB
  auto v1bytes=[&](size_t U)->size_t{
    size_t a=U*64;
    size_t b=K*4+K*4+M*4+M*4+(K/1024)*4+QCAP*4+1024;
    size_t m1=a>b?a:b;
    if(partial_bytes>m1) m1=partial_bytes;
    if(partial2_bytes>m1) m1=partial2_bytes;
    return m1;
  };
  auto need=[&](int lC,int lU)->size_t{
    size_t C=1ull<<lC, U=1ull<<lU, s=0;
    auto al=[&](size_t b){ s=(s+255)&~(size_t)255; s+=b; };
    al(4); al(M*4); al(M*4); al(C*8); al(C*4); al(U*4); al(U*64); al(v1bytes(U));
    return s+256;
  };
  const int prefs[4][2]={{22,20},{21,20},{21,19},{20,18}};
  int lC=0,lU=0;
  for(int i=0;i<4;i++){ if(need(prefs[i][0],prefs[i][1])<=ws_size){ lC=prefs[i][0]; lU=prefs[i][1]; break; } }
  if(!lC){
    hipMemsetAsync(d_out,0,(size_t)out_size*sizeof(float),stream);
    k_diag<<<1,1,0,stream>>>(out,(float)(ws_size>>20));
    return;
  }

  size_t C=1ull<<lC, Ucap=1ull<<lU; u32 cmask=(u32)(C-1);
  char* base=(char*)d_ws; size_t offb=0;
  auto carve=[&](size_t b)->char*{ offb=(offb+255)&~(size_t)255; char* p=base+offb; offb+=b; return p; };
  u32*   counter=(u32*)carve(4);
  u32*   inv    =(u32*)carve(M*4);
  float* bary   =(float*)carve(M*4);
  u64*   tabk   =(u64*)carve(C*8);
  u32*   tuid   =(u32*)carve(C*4);
  u32*   uidslot=(u32*)carve(Ucap*4);
  float* v0     =(float*)carve(Ucap*64);
  float* v1     =(float*)carve(v1bytes(Ucap));

  u32*   hist =(u32*)v1;
  u32*   histT=hist+K;
  u32*   skey =histT+K;
  float* sw   =(float*)(skey+M);
  u32*   bsum =(u32*)(sw+M);
  u32*   q    =bsum+(K/1024);
  u32*   qn   =q+QCAP;
  float* partial =(float*)v1;   // tier-2 alias
  float* partial2=(float*)v1;   // tier-1 alias

  hipMemsetAsync(counter,0,4,stream);
  hipMemsetAsync(tabk,0xFF,C*8,stream);
  hipMemsetAsync(v0,0,Ucap*64,stream);

  const int B=256;
  k_setup    <<<(N+B-1)/B,B,0,stream>>>(feat,N,tabk,cmask,inv,bary);
  k_uid      <<<(u32)((C+B-1)/B),B,0,stream>>>(tabk,(u32)C,(u32)Ucap,tuid,uidslot,counter);
  k_translate<<<(u32)((M+B-1)/B),B,0,stream>>>(inv,tuid,M);

  // ---- tier 1: single-pass channel-split (dead unless en && U<=U2CAP) ----
  if(en){
    k_saccum2<<<2*S2,1024,LDS2B,stream>>>(inv,bary,values,counter,en,N,partial2);
    k_reduce2<<<(2*U2CAP*8+B-1)/B,B,0,stream>>>(partial2,counter,en,v0);
  }
  u32 loU = en ? U2CAP : 0;

  // ---- tier 2: pass path (dead unless loU < U <= THRESH) ----
  k_saccum<<<TOTAL_B,1024,0,stream>>>(inv,bary,values,counter,(u32)Ucap,loU,N,partial);
  k_reduce<<<PMAX*(RPP/16),B,0,stream>>>(partial,counter,(u32)Ucap,loU,v0);

  // ---- tier 3: partition path (dead unless U > THRESH) ----
  hipMemsetAsync(qn,0,4,stream);
  k_hist <<<nb,B,0,stream>>>(inv,counter,hist,M);
  {
    dim3 g((BINS+31)/32,(nb+31)/32);
    k_transpose<<<g,B,0,stream>>>(hist,histT,nb,BINS,counter);
  }
  u32 sb=(u32)(K/1024);
  k_scan1<<<sb,B,0,stream>>>(histT,bsum,counter);
  k_scan2<<<1 ,B,0,stream>>>(bsum,sb,counter);
  k_scan3<<<sb,B,0,stream>>>(histT,bsum,counter);
  k_part <<<nb,B,0,stream>>>(inv,bary,histT,nb,skey,sw,M,counter);
  k_queue<<<(BINS+B-1)/B,B,0,stream>>>(histT,nb,M,q,qn,counter);
  u32 rows=(u32)(Ucap>>12);
  k_accum<<<QCAP,B,0,stream>>>(q,qn,skey,sw,values,histT,nb,rows,M,v0);

  const long long P[5]={1ll,2048ll,1ll<<22,1ll<<33,1ll<<44};
  const long long SUM=P[0]+P[1]+P[2]+P[3]+P[4];
  u32 gb=(u32)((Ucap+B-1)/B);
  float* a=v0; float* bb=v1;
  for(int j=0;j<6;j++){
    long long delta=(j<5)? (SUM-6*P[4-j]) : SUM;
    k_blur<<<gb,B,0,stream>>>(tabk,tuid,cmask,uidslot,counter,(u32)Ucap,delta,a,bb);
    float* t=a; a=bb; bb=t;
  }
  k_slice<<<(N+B-1)/B,B,0,stream>>>(inv,bary,a,N,out);
}

// Round 13
// 1213.800 us; speedup vs baseline: 1.0411x; 1.0411x over previous
//
#include <hip/hip_runtime.h>
#include <stdint.h>

typedef unsigned long long u64;
typedef unsigned int u32;

static constexpr u64 KEMPTY = ~0ull;
static constexpr int PROBE_CAP = 32768;
static constexpr u32 BINS  = 4096;
static constexpr u32 CHUNK = 4096;
static constexpr u32 SPLIT = 2048;

// ---- tier-2 pass path (U2CAP < U <= THRESH) ----
static constexpr u32 RPP    = 960;
static constexpr u32 TOTAL_B= 512;
static constexpr u32 PMAX   = 24;
static constexpr u32 THRESH = RPP*PMAX;       // 23040

// ---- tier-1 single-pass channel-split path (U <= U2CAP), static 158.4KB LDS ----
static constexpr u32 U2CAP = 4400;            // 4400*9*4 = 158400 B <= 160 KiB/WG on gfx950
static constexpr u32 S2    = 128;             // point subranges; grid = 2*S2 = 256 blocks

static __device__ __forceinline__ u64 mix64(u64 x){
  x ^= x >> 30; x *= 0xbf58476d1ce4e5b9ull;
  x ^= x >> 27; x *= 0x94d049bb133111ebull;
  x ^= x >> 31; return x;
}

static __device__ __forceinline__ long long lookup_slot(const u64* __restrict__ tk, u32 cmask, u64 code){
  u32 h = (u32)mix64(code) & cmask;
#pragma unroll 1
  for(int p=0;p<PROBE_CAP;p++){
    u64 cur = tk[h];
    if(cur==code) return (long long)h;
    if(cur==KEMPTY) return -1;
    h=(h+1)&cmask;
  }
  return -1;
}

static __device__ __forceinline__ void atomAddF(float* p, float v){
#if defined(__gfx90a__) || defined(__gfx940__) || defined(__gfx941__) || defined(__gfx942__) || defined(__gfx950__)
  unsafeAtomicAdd(p, v);
#else
  atomicAdd(p, v);
#endif
}

static __device__ __forceinline__ void lds_add(float* p, float v){
  __hip_atomic_fetch_add(p, v, __ATOMIC_RELAXED, __HIP_MEMORY_SCOPE_WORKGROUP);
}
static __device__ __forceinline__ void lds_addu(u32* p, u32 v){
  __hip_atomic_fetch_add(p, v, __ATOMIC_RELAXED, __HIP_MEMORY_SCOPE_WORKGROUP);
}
static __device__ __forceinline__ u32 lds_addu_rtn(u32* p, u32 v){
  return __hip_atomic_fetch_add(p, v, __ATOMIC_RELAXED, __HIP_MEMORY_SCOPE_WORKGROUP);
}

static __device__ __forceinline__ void row_load(const float* __restrict__ p, float* o){
  const float4* q=(const float4*)p;
#pragma unroll
  for(int i=0;i<4;i++){ float4 v=q[i]; o[4*i]=v.x; o[4*i+1]=v.y; o[4*i+2]=v.z; o[4*i+3]=v.w; }
}
static __device__ __forceinline__ void row_store(float* __restrict__ p, const float* o){
  float4* q=(float4*)p;
#pragma unroll
  for(int i=0;i<4;i++) q[i]=make_float4(o[4*i],o[4*i+1],o[4*i+2],o[4*i+3]);
}

// ---------------- kernel 1: elevate/rank/bary + table insert; stores SLOT in inv ----------------
__global__ void __launch_bounds__(256)
k_setup(const float* __restrict__ feat, int N,
        u64* __restrict__ tabk, u32 cmask,
        u32* __restrict__ inv_slot, float* __restrict__ bary)
{
#pragma clang fp contract(off)
  int n = blockIdx.x*256 + threadIdx.x;
  if(n>=N) return;

  const float s0=3.4641016151377544f, s1=2.0f, s2=1.4142135623730951f,
              s3=1.0954451150103321f, s4=0.8944271909999159f;
  float c[5];
  c[0]=feat[n*5+0]*s0; c[1]=feat[n*5+1]*s1; c[2]=feat[n*5+2]*s2;
  c[3]=feat[n*5+3]*s3; c[4]=feat[n*5+4]*s4;

  float sfx[6]; sfx[5]=0.f;
#pragma unroll
  for(int i=4;i>=0;i--) sfx[i]=sfx[i+1]+c[i];
  float el[6];
  el[0]=sfx[0];
#pragma unroll
  for(int i=1;i<6;i++) el[i]=sfx[i]-(float)i*c[i-1];

  const float down=1.0f/6.0f;
  float rd[6], rem0[6], rdsum=0.f;
#pragma unroll
  for(int i=0;i<6;i++){ rd[i]=rintf(el[i]*down); rem0[i]=rd[i]*6.0f; rdsum+=rd[i]; }
  int sumi=(int)rdsum;

  float diff[6];
#pragma unroll
  for(int i=0;i<6;i++) diff[i]=(el[i]-rem0[i])*down;

  int rank[6];
#pragma unroll
  for(int i=0;i<6;i++){
    int r=0;
#pragma unroll
    for(int j=0;j<6;j++)
      r += (diff[j]>diff[i]) || (diff[j]==diff[i] && j<i);
    rank[i]=r+sumi;
  }
  int rem0i[6];
#pragma unroll
  for(int i=0;i<6;i++){
    rem0i[i]=(int)rem0[i];
    int sh=(rank[i]<0)-(rank[i]>5);
    rank[i]+=6*sh; rem0i[i]+=6*sh;
  }

  float b[7]={0.f,0.f,0.f,0.f,0.f,0.f,0.f};
#pragma unroll
  for(int i=0;i<6;i++){
    float t=(el[i]-(float)rem0i[i])*down;
    int k0=5-rank[i]; if(k0>=0&&k0<7) b[k0]+=t;
  }
#pragma unroll
  for(int i=0;i<6;i++){
    float t=(el[i]-(float)rem0i[i])*down;
    int k1=6-rank[i]; if(k1>=0&&k1<7) b[k1]-=t;
  }
  bary[(size_t)n*6+0]=(b[0]+1.0f)+b[6];
#pragma unroll
  for(int r=1;r<6;r++) bary[(size_t)n*6+r]=b[r];

#pragma unroll 1
  for(int r=0;r<6;r++){
    long long code=0;
#pragma unroll
    for(int i=0;i<5;i++){
      int key = rem0i[i] + ((rank[i] >= 6-r) ? (r-6) : r);
      code = code*2048 + (long long)(key+1024);
    }
    u32 h=(u32)mix64((u64)code)&cmask;
    u32 slot=0xFFFFFFFFu;
#pragma unroll 1
    for(int p=0;p<PROBE_CAP;p++){
      u64 cur=tabk[h];
      if(cur==(u64)code){ slot=h; break; }
      if(cur==KEMPTY){
        u64 old=atomicCAS((unsigned long long*)&tabk[h], KEMPTY, (u64)code);
        if(old==KEMPTY || old==(u64)code){ slot=h; break; }
      } else {
        h=(h+1)&cmask;
      }
    }
    inv_slot[(size_t)n*6+r]=slot;
  }
}

// ---------------- kernel 2: compact uids ----------------
__global__ void __launch_bounds__(256)
k_uid(const u64* __restrict__ tabk, u32 C, u32 Ucap, u32* __restrict__ tuid,
      u32* __restrict__ uidslot, u32* __restrict__ counter)
{
  u32 s=blockIdx.x*256+threadIdx.x;
  if(s>=C) return;
  if(tabk[s]==KEMPTY) return;
  u32 uid=atomicAdd(counter,1u);
  if(uid<Ucap) uidslot[uid]=s; else uid=0;
  tuid[s]=uid;
}

// ---------------- kernel 3: slot -> uid translation ----------------
__global__ void __launch_bounds__(256)
k_translate(u32* __restrict__ inv, const u32* __restrict__ tuid, size_t M)
{
  size_t i=(size_t)blockIdx.x*256+threadIdx.x;
  if(i<M) inv[i]=tuid[inv[i]];
}

// ================= TIER 1: single-pass channel-split splat (U <= U2CAP) =================
// 256 blocks (1/CU, 158.4KB static LDS). block = (channel-half cs, point-subrange sub).
// Every ds_add runs with all 64 lanes active; inv/bary scanned 2x total (vs P=4),
// values half-rows only. Falsifies per-instruction vs per-lane LDS-atomic cost.
__global__ void __launch_bounds__(1024, 1)
k_saccum2(const u32* __restrict__ inv, const float* __restrict__ bary,
          const float* __restrict__ values, const u32* __restrict__ counter,
          int N, float* __restrict__ partial2)
{
  __shared__ float acc2[U2CAP*9];
  u32 U=*counter;
  if(U>U2CAP) return;
  u32 j=blockIdx.x;
  u32 cs=j&1, sub=j>>1;
  u32 t=threadIdx.x;
  u32 tot=U*9;
  for(u32 x=t;x<tot;x+=1024) acc2[x]=0.f;
  __syncthreads();

  size_t p0=((size_t)sub*(size_t)N)/S2;
  size_t p1=((size_t)(sub+1)*(size_t)N)/S2;
  const float4* vbase=(const float4*)values;
  for(size_t i=p0+t;i<p1;i+=1024){
    const u32* ip=inv+i*6;
    const float* bp=bary+i*6;
    float4 va=vbase[i*4+cs*2];
    float4 vb=vbase[i*4+cs*2+1];
#pragma unroll
    for(int r=0;r<6;r++){
      u32 a=ip[r]*9;
      float w=bp[r];
      lds_add(&acc2[a+0], w*va.x);
      lds_add(&acc2[a+1], w*va.y);
      lds_add(&acc2[a+2], w*va.z);
      lds_add(&acc2[a+3], w*va.w);
      lds_add(&acc2[a+4], w*vb.x);
      lds_add(&acc2[a+5], w*vb.y);
      lds_add(&acc2[a+6], w*vb.z);
      lds_add(&acc2[a+7], w*vb.w);
    }
  }
  __syncthreads();
  float* dst=partial2+(size_t)j*(U2CAP*9);
  for(u32 x=t;x<tot;x+=1024) dst[x]=acc2[x];
}

// sum the S2 sub-partials of each channel-set into v0
__global__ void __launch_bounds__(256)
k_reduce2(const float* __restrict__ partial2, const u32* __restrict__ counter,
          float* __restrict__ v0)
{
  u32 U=*counter;
  if(U>U2CAP) return;
  u32 x=blockIdx.x*256+threadIdx.x;
  u32 csz=U*8u;
  if(x>=2u*csz) return;
  u32 cs=x/csz; u32 rem=x-cs*csz;
  u32 u=rem>>3, k=rem&7;
  const float* base=partial2+(size_t)cs*(U2CAP*9)+(size_t)u*9+k;
  float s=0.f;
  for(u32 ss=0;ss<S2;ss++) s+=base[(size_t)ss*2u*(U2CAP*9)];
  v0[(size_t)u*16+cs*8+k]=s;
}

// ================= TIER 2: pass-based stream splat (U2CAP < U <= THRESH) =================
__global__ void __launch_bounds__(1024, 8)
k_saccum(const u32* __restrict__ inv, const float* __restrict__ bary,
         const float* __restrict__ values, const u32* __restrict__ counter,
         u32 Ucap, u32 loU, int N, float* __restrict__ partial)
{
  __shared__ float acc[RPP*17];
  u32 U=*counter; if(U>Ucap) U=Ucap;
  if(U<=loU || U>THRESH) return;
  u32 P=(U+RPP-1)/RPP;
  u32 S=TOTAL_B/P;
  u32 j=blockIdx.x;
  if(j>=P*S) return;
  u32 pass=j/S, sub=j-pass*S;
  u32 lo=pass*RPP;
  u32 t=threadIdx.x;
  for(u32 x=t;x<RPP*17;x+=1024) acc[x]=0.f;
  __syncthreads();

  size_t p0=((size_t)sub*(size_t)N)/S;
  size_t p1=((size_t)(sub+1)*(size_t)N)/S;
  for(size_t i=p0+t;i<p1;i+=1024){
    const u32* ip=inv+i*6;
    const float* bp=bary+i*6;
    u32 u[6]; float w[6];
#pragma unroll
    for(int r=0;r<6;r++){ u[r]=ip[r]-lo; w[r]=bp[r]; }
    bool any=false;
#pragma unroll
    for(int r=0;r<6;r++) any = any | (u[r]<RPP);
    if(!any) continue;
    float v[16];
    row_load(values+(size_t)i*16, v);
#pragma unroll
    for(int r=0;r<6;r++){
      if(u[r]<RPP){
        u32 a=u[r]*17; float ww=w[r];
#pragma unroll
        for(int k=0;k<16;k++) lds_add(&acc[a+k], ww*v[k]);
      }
    }
  }
  __syncthreads();
  float* dst=partial+(size_t)j*(RPP*17);
  for(u32 x=t;x<RPP*17;x+=1024) dst[x]=acc[x];
}

__global__ void __launch_bounds__(256)
k_reduce(const float* __restrict__ partial, const u32* __restrict__ counter,
         u32 Ucap, u32 loU, float* __restrict__ v0)
{
  u32 U=*counter; if(U>Ucap) U=Ucap;
  if(U<=loU || U>THRESH) return;
  u32 P=(U+RPP-1)/RPP, S=TOTAL_B/P;
  const u32 RG=RPP/16;
  u32 bid=blockIdx.x;
  u32 pass=bid/RG, rg=bid-pass*RG;
  if(pass>=P) return;
  u32 t=threadIdx.x;
  u32 r16=t>>4, k=t&15;
  u32 lrow=rg*16+r16;
  u32 gu=pass*RPP+lrow;
  const float* base=partial+((size_t)pass*S)*(RPP*17)+(size_t)lrow*17+k;
  float s=0.f;
  for(u32 ss=0;ss<S;ss++) s+=base[(size_t)ss*(RPP*17)];
  if(gu<U) v0[(size_t)gu*16+k]=s;
}

// ================= TIER 3: partition path (U > THRESH) =================
__global__ void __launch_bounds__(256)
k_hist(const u32* __restrict__ inv, const u32* __restrict__ counter,
       u32* __restrict__ hist, size_t M)
{
  if(*counter<=THRESH) return;
  __shared__ u32 h[BINS];
  u32 t=threadIdx.x, b=blockIdx.x;
#pragma unroll
  for(int j=0;j<(int)(BINS/256);j++) h[t+j*256]=0;
  __syncthreads();
  size_t base=(size_t)b*CHUNK;
#pragma unroll
  for(int j=0;j<(int)(CHUNK/256);j++){
    size_t i=base + (size_t)j*256 + t;
    if(i<M){
      u32 u=inv[i];
      lds_addu(&h[u&(BINS-1)],1u);
    }
  }
  __syncthreads();
#pragma unroll
  for(int j=0;j<(int)(BINS/256);j++){
    u32 bin=t+j*256;
    hist[(size_t)b*BINS+bin]=h[bin];
  }
}

__global__ void __launch_bounds__(256)
k_transpose(const u32* __restrict__ in, u32* __restrict__ out, u32 R, u32 C,
            const u32* __restrict__ counter)
{
  if(*counter<=THRESH) return;
  __shared__ u32 tile[32][33];
  u32 bx=blockIdx.x, by=blockIdx.y;
  u32 tx=threadIdx.x&31, ty=threadIdx.x>>5;
  u32 c0=bx*32, r0=by*32;
#pragma unroll
  for(u32 j=0;j<32;j+=8){
    u32 r=r0+ty+j, c=c0+tx;
    if(r<R && c<C) tile[ty+j][tx]=in[(size_t)r*C+c];
  }
  __syncthreads();
#pragma unroll
  for(u32 j=0;j<32;j+=8){
    u32 c=c0+ty+j, r=r0+tx;
    if(c<C && r<R) out[(size_t)c*R+r]=tile[tx][ty+j];
  }
}

__global__ void __launch_bounds__(256)
k_scan1(const u32* __restrict__ v, u32* __restrict__ bsum, const u32* __restrict__ counter)
{
  if(*counter<=THRESH) return;
  __shared__ u32 sm[256];
  u32 t=threadIdx.x, b=blockIdx.x;
  size_t base=((size_t)b*256+t)*4;
  u32 s=v[base]+v[base+1]+v[base+2]+v[base+3];
  sm[t]=s; __syncthreads();
  for(int o=128;o>0;o>>=1){ if(t<(u32)o) sm[t]+=sm[t+o]; __syncthreads(); }
  if(t==0) bsum[b]=sm[0];
}

__global__ void __launch_bounds__(256)
k_scan2(u32* __restrict__ bsum, u32 nb, const u32* __restrict__ counter)
{
  if(*counter<=THRESH) return;
  __shared__ u32 sm[256];
  u32 t=threadIdx.x;
  u32 per=(nb+255)/256;
  u32 lo=t*per, hi=lo+per; if(hi>nb) hi=nb; if(lo>nb) lo=nb;
  u32 tot=0;
  for(u32 i=lo;i<hi;i++) tot+=bsum[i];
  sm[t]=tot; __syncthreads();
  for(int o=1;o<256;o<<=1){
    u32 v=sm[t]; u32 a=(t>=(u32)o)?sm[t-o]:0u; __syncthreads();
    sm[t]=v+a; __syncthreads();
  }
  u32 run=sm[t]-tot;
  for(u32 i=lo;i<hi;i++){ u32 c=bsum[i]; bsum[i]=run; run+=c; }
}

__global__ void __launch_bounds__(256)
k_scan3(u32* __restrict__ v, const u32* __restrict__ bsum, const u32* __restrict__ counter)
{
  if(*counter<=THRESH) return;
  __shared__ u32 sm[256];
  u32 t=threadIdx.x, b=blockIdx.x;
  size_t base=((size_t)b*256+t)*4;
  u32 c[4]; u32 tot=0;
#pragma unroll
  for(int j=0;j<4;j++){ c[j]=v[base+j]; tot+=c[j]; }
  sm[t]=tot; __syncthreads();
  for(int o=1;o<256;o<<=1){
    u32 x=sm[t]; u32 a=(t>=(u32)o)?sm[t-o]:0u; __syncthreads();
    sm[t]=x+a; __syncthreads();
  }
  u32 run=bsum[b]+sm[t]-tot;
#pragma unroll
  for(int j=0;j<4;j++){ v[base+j]=run; run+=c[j]; }
}

__global__ void __launch_bounds__(256)
k_part(const u32* __restrict__ inv, const float* __restrict__ bary,
       const u32* __restrict__ histT, u32 nb,
       u32* __restrict__ skey, float* __restrict__ sw, size_t M,
       const u32* __restrict__ counter)
{
  if(*counter<=THRESH) return;
  __shared__ u32 cur[BINS];
  u32 t=threadIdx.x, b=blockIdx.x;
#pragma unroll
  for(int j=0;j<(int)(BINS/256);j++){
    u32 bin=t+j*256;
    cur[bin]=histT[(size_t)bin*nb+b];
  }
  __syncthreads();
  size_t base=(size_t)b*CHUNK;
#pragma unroll
  for(int j=0;j<(int)(CHUNK/256);j++){
    size_t i=base+(size_t)j*256+t;
    if(i<M){
      u32 u=inv[i];
      u32 pos=lds_addu_rtn(&cur[u&(BINS-1)],1u);
      skey[pos]=((u>>12)<<20)|((u32)(i/6u));
      sw[pos]=bary[i];
    }
  }
}

__global__ void __launch_bounds__(256)
k_queue(const u32* __restrict__ histT, u32 nb, size_t M,
        u32* __restrict__ q, u32* __restrict__ qn, const u32* __restrict__ counter)
{
  if(*counter<=THRESH) return;
  u32 b=blockIdx.x*256+threadIdx.x;
  if(b>=BINS) return;
  size_t s=histT[(size_t)b*nb];
  size_t e=(b+1<BINS)? (size_t)histT[(size_t)(b+1)*nb] : M;
  u32 sz=(u32)(e-s);
  if(sz==0) return;
  u32 G=(sz+SPLIT-1)/SPLIT; if(G>1023u) G=1023u;
  u32 base=atomicAdd(qn,G);
  for(u32 g=0; g<G; g++) q[base+g] = b | (g<<12) | (G<<22);
}

__global__ void __launch_bounds__(256)
k_accum(const u32* __restrict__ q, const u32* __restrict__ qn,
        const u32* __restrict__ skey, const float* __restrict__ sw,
        const float* __restrict__ values, const u32* __restrict__ histT,
        u32 nb, u32 rows, size_t M, float* __restrict__ v0)
{
  __shared__ float acc[4352];
  u32 j=blockIdx.x;
  if(j>=*qn) return;
  u32 ent=q[j];
  u32 b=ent&4095u, g=(ent>>12)&1023u, G=ent>>22;
  size_t s0=histT[(size_t)b*nb];
  size_t e0=(b+1<BINS)? (size_t)histT[(size_t)(b+1)*nb] : M;
  u32 sz=(u32)(e0-s0);
  u32 chunk=(sz+G-1)/G;
  size_t s=s0+(size_t)g*chunk;
  size_t e=s+chunk; if(e>e0) e=e0;

  u32 t=threadIdx.x;
  for(u32 x=t;x<rows*17;x+=256) acc[x]=0.f;
  __syncthreads();

  if(G==1){
    size_t base=s;
    for(; base+512<=e; base+=512){
      size_t i0=base+t, i1=base+256+t;
      u32 key0=skey[i0], key1=skey[i1];
      float w0=sw[i0], w1=sw[i1];
      float r0[16], r1[16];
      row_load(values+(size_t)(key0&0xFFFFFu)*16, r0);
      row_load(values+(size_t)(key1&0xFFFFFu)*16, r1);
      u32 a0=(key0>>20)*17, a1=(key1>>20)*17;
#pragma unroll
      for(int k=0;k<16;k++) lds_add(&acc[a0+k], w0*r0[k]);
#pragma unroll
      for(int k=0;k<16;k++) lds_add(&acc[a1+k], w1*r1[k]);
    }
    for(; base<e; base+=256){
      size_t ei=base+t;
      if(ei<e){
        u32 key=skey[ei]; float w=sw[ei];
        float r[16];
        row_load(values+(size_t)(key&0xFFFFFu)*16, r);
        u32 a=(key>>20)*17;
#pragma unroll
        for(int k=0;k<16;k++) lds_add(&acc[a+k], w*r[k]);
      }
    }
  } else {
    u32 gr=t>>4, k=t&15;
    size_t base=s;
    for(; base+128<=e; base+=128){
      u32 key[8]; float w[8]; float x[8];
#pragma unroll
      for(int u8=0;u8<8;u8++){ size_t ei=base+(size_t)u8*16+gr; key[u8]=skey[ei]; w[u8]=sw[ei]; }
#pragma unroll
      for(int u8=0;u8<8;u8++){ x[u8]=values[(size_t)(key[u8]&0xFFFFFu)*16+k]; }
#pragma unroll
      for(int u8=0;u8<8;u8++) lds_add(&acc[(key[u8]>>20)*17+k], w[u8]*x[u8]);
    }
    for(; base<e; base+=16){
      size_t ei=base+gr;
      if(ei<e){
        u32 key=skey[ei]; float w=sw[ei];
        float x=values[(size_t)(key&0xFFFFFu)*16+k];
        lds_add(&acc[(key>>20)*17+k], w*x);
      }
    }
  }
  __syncthreads();

  if(G==1){
    for(u32 x=t;x<rows*16;x+=256){
      u32 row=x>>4, kk=x&15;
      v0[(size_t)((row<<12)|b)*16+kk]=acc[row*17+kk];
    }
  } else {
    for(u32 x=t;x<rows*16;x+=256){
      u32 row=x>>4, kk=x&15;
      float a=acc[row*17+kk];
      if(a!=0.f) atomAddF(&v0[(size_t)((row<<12)|b)*16+kk], a);
    }
  }
}

// ---------------- blur ----------------
__global__ void __launch_bounds__(256)
k_blur(const u64* __restrict__ tabk, const u32* __restrict__ tuid, u32 cmask,
       const u32* __restrict__ uidslot, const u32* __restrict__ counter, u32 Ucap,
       long long delta, const float* __restrict__ vin, float* __restrict__ vout)
{
  u32 m=blockIdx.x*256+threadIdx.x;
  u32 U=*counter; if(U>Ucap) U=Ucap;
  if(m>=U) return;
  long long code=(long long)tabk[uidslot[m]];
  long long sp=lookup_slot(tabk,cmask,(u64)(code+delta));
  long long sm=lookup_slot(tabk,cmask,(u64)(code-delta));
  float acc[16];
  row_load(vin+(size_t)m*16, acc);
#pragma unroll
  for(int k=0;k<16;k++) acc[k]*=0.5f;
  if(sp>=0){
    u32 u=tuid[sp]; float t[16]; row_load(vin+(size_t)u*16,t);
#pragma unroll
    for(int k=0;k<16;k++) acc[k]+=0.25f*t[k];
  }
  if(sm>=0){
    u32 u=tuid[sm]; float t[16]; row_load(vin+(size_t)u*16,t);
#pragma unroll
    for(int k=0;k<16;k++) acc[k]+=0.25f*t[k];
  }
  row_store(vout+(size_t)m*16, acc);
}

// ---------------- slice ----------------
__global__ void __launch_bounds__(256)
k_slice(const u32* __restrict__ inv, const float* __restrict__ bary,
        const float* __restrict__ val, int N, float* __restrict__ out)
{
  int n=blockIdx.x*256+threadIdx.x;
  if(n>=N) return;
  u32 u[6]; float w[6];
#pragma unroll
  for(int r=0;r<6;r++){ u[r]=inv[(size_t)n*6+r]; w[r]=bary[(size_t)n*6+r]; }
  float t6[6][16];
#pragma unroll
  for(int r=0;r<6;r++) row_load(val+(size_t)u[r]*16, t6[r]);
  float acc[16];
#pragma unroll
  for(int k=0;k<16;k++){
    float a=w[0]*t6[0][k];
#pragma unroll
    for(int r=1;r<6;r++) a+=w[r]*t6[r][k];
    acc[k]=a;
  }
  const float alpha=0.9696969696969697f;
  float4* q=(float4*)(out+(size_t)n*16);
#pragma unroll
  for(int i=0;i<4;i++) q[i]=make_float4(alpha*acc[4*i],alpha*acc[4*i+1],alpha*acc[4*i+2],alpha*acc[4*i+3]);
}

__global__ void k_diag(float* out, float v){ out[0]=v; }

// ---------------- host ----------------
extern "C" void kernel_launch(void* const* d_in, const int* in_sizes, int n_in,
                              void* d_out, int out_size, void* d_ws, size_t ws_size,
                              hipStream_t stream)
{
  const float* feat   =(const float*)d_in[0];
  const float* values =(const float*)d_in[1];
  float* out=(float*)d_out;
  int N=in_sizes[0]/5;
  size_t M=(size_t)N*6;

  u32 nb=(u32)((M+CHUNK-1)/CHUNK);
  size_t K=(size_t)nb*BINS;
  const u32 QCAP=16384;

  // v1 union: partition scratch OR tier-2 partials OR tier-1 partials
  size_t partial_bytes =(size_t)TOTAL_B*(RPP*17)*4;          // 33.4 MB
  size_t partial2_bytes=(size_t)(2*S2)*(size_t)(U2CAP*9)*4;  // 40.5 MB
  auto v1bytes=[&](size_t U)->size_t{
    size_t a=U*64;
    size_t b=K*4+K*4+M*4+M*4+(K/1024)*4+QCAP*4+1024;
    size_t m1=a>b?a:b;
    if(partial_bytes>m1) m1=partial_bytes;
    if(partial2_bytes>m1) m1=partial2_bytes;
    return m1;
  };
  auto need=[&](int lC,int lU)->size_t{
    size_t C=1ull<<lC, U=1ull<<lU, s=0;
    auto al=[&](size_t b){ s=(s+255)&~(size_t)255; s+=b; };
    al(4); al(M*4); al(M*4); al(C*8); al(C*4); al(U*4); al(U*64); al(v1bytes(U));
    return s+256;
  };
  const int prefs[4][2]={{22,20},{21,20},{21,19},{20,18}};
  int lC=0,lU=0;
  for(int i=0;i<4;i++){ if(need(prefs[i][0],prefs[i][1])<=ws_size){ lC=prefs[i][0]; lU=prefs[i][1]; break; } }
  if(!lC){
    hipMemsetAsync(d_out,0,(size_t)out_size*sizeof(float),stream);
    k_diag<<<1,1,0,stream>>>(out,(float)(ws_size>>20));
    return;
  }

  size_t C=1ull<<lC, Ucap=1ull<<lU; u32 cmask=(u32)(C-1);
  char* base=(char*)d_ws; size_t offb=0;
  auto carve=[&](size_t b)->char*{ offb=(offb+255)&~(size_t)255; char* p=base+offb; offb+=b; return p; };
  u32*   counter=(u32*)carve(4);
  u32*   inv    =(u32*)carve(M*4);
  float* bary   =(float*)carve(M*4);
  u64*   tabk   =(u64*)carve(C*8);
  u32*   tuid   =(u32*)carve(C*4);
  u32*   uidslot=(u32*)carve(Ucap*4);
  float* v0     =(float*)carve(Ucap*64);
  float* v1     =(float*)carve(v1bytes(Ucap));

  u32*   hist =(u32*)v1;
  u32*   histT=hist+K;
  u32*   skey =histT+K;
  float* sw   =(float*)(skey+M);
  u32*   bsum =(u32*)(sw+M);
  u32*   q    =bsum+(K/1024);
  u32*   qn   =q+QCAP;
  float* partial =(float*)v1;   // tier-2 alias
  float* partial2=(float*)v1;   // tier-1 alias

  hipMemsetAsync(counter,0,4,stream);
  hipMemsetAsync(tabk,0xFF,C*8,stream);
  hipMemsetAsync(v0,0,Ucap*64,stream);

  const int B=256;
  k_setup    <<<(N+B-1)/B,B,0,stream>>>(feat,N,tabk,cmask,inv,bary);
  k_uid      <<<(u32)((C+B-1)/B),B,0,stream>>>(tabk,(u32)C,(u32)Ucap,tuid,uidslot,counter);
  k_translate<<<(u32)((M+B-1)/B),B,0,stream>>>(inv,tuid,M);

  // ---- tier 1: single-pass channel-split (dead unless U<=U2CAP) ----
  k_saccum2<<<2*S2,1024,0,stream>>>(inv,bary,values,counter,N,partial2);
  k_reduce2<<<(2*U2CAP*8+B-1)/B,B,0,stream>>>(partial2,counter,v0);

  // ---- tier 2: pass path (dead unless U2CAP < U <= THRESH) ----
  k_saccum<<<TOTAL_B,1024,0,stream>>>(inv,bary,values,counter,(u32)Ucap,U2CAP,N,partial);
  k_reduce<<<PMAX*(RPP/16),B,0,stream>>>(partial,counter,(u32)Ucap,U2CAP,v0);

  // ---- tier 3: partition path (dead unless U > THRESH) ----
  hipMemsetAsync(qn,0,4,stream);
  k_hist <<<nb,B,0,stream>>>(inv,counter,hist,M);
  {
    dim3 g((BINS+31)/32,(nb+31)/32);
    k_transpose<<<g,B,0,stream>>>(hist,histT,nb,BINS,counter);
  }
  u32 sb=(u32)(K/1024);
  k_scan1<<<sb,B,0,stream>>>(histT,bsum,counter);
  k_scan2<<<1 ,B,0,stream>>>(bsum,sb,counter);
  k_scan3<<<sb,B,0,stream>>>(histT,bsum,counter);
  k_part <<<nb,B,0,stream>>>(inv,bary,histT,nb,skey,sw,M,counter);
  k_queue<<<(BINS+B-1)/B,B,0,stream>>>(histT,nb,M,q,qn,counter);
  u32 rows=(u32)(Ucap>>12);
  k_accum<<<QCAP,B,0,stream>>>(q,qn,skey,sw,values,histT,nb,rows,M,v0);

  const long long P[5]={1ll,2048ll,1ll<<22,1ll<<33,1ll<<44};
  const long long SUM=P[0]+P[1]+P[2]+P[3]+P[4];
  u32 gb=(u32)((Ucap+B-1)/B);
  float* a=v0; float* bb=v1;
  for(int j=0;j<6;j++){
    long long delta=(j<5)? (SUM-6*P[4-j]) : SUM;
    k_blur<<<gb,B,0,stream>>>(tabk,tuid,cmask,uidslot,counter,(u32)Ucap,delta,a,bb);
    float* t=a; a=bb; bb=t;
  }
  k_slice<<<(N+B-1)/B,B,0,stream>>>(inv,bary,a,N,out);
}

// Round 14
// 1195.907 us; speedup vs baseline: 1.0567x; 1.0150x over previous
//
#include <hip/hip_runtime.h>
#include <stdint.h>

typedef unsigned long long u64;
typedef unsigned int u32;

static constexpr u64 KEMPTY = ~0ull;
static constexpr int PROBE_CAP = 32768;
static constexpr u32 BINS  = 4096;
static constexpr u32 CHUNK = 4096;
static constexpr u32 SPLIT = 2048;

// ---- tier-2 pass path (U4CAP < U <= THRESH) ----
static constexpr u32 RPP    = 960;
static constexpr u32 TOTAL_B= 512;
static constexpr u32 PMAX   = 24;
static constexpr u32 THRESH = RPP*PMAX;       // 23040

// ---- tier-1 single-pass 4-way channel-split (U <= U4CAP), static 162.5KB LDS ----
static constexpr u32 U4CAP = 8128;            // 8128*5*4 = 162560 B <= 160 KiB/WG (gfx950)
static constexpr u32 S4    = 64;              // point subranges; grid = 4*S4 = 256 blocks

static __device__ __forceinline__ u64 mix64(u64 x){
  x ^= x >> 30; x *= 0xbf58476d1ce4e5b9ull;
  x ^= x >> 27; x *= 0x94d049bb133111ebull;
  x ^= x >> 31; return x;
}

static __device__ __forceinline__ long long lookup_slot(const u64* __restrict__ tk, u32 cmask, u64 code){
  u32 h = (u32)mix64(code) & cmask;
#pragma unroll 1
  for(int p=0;p<PROBE_CAP;p++){
    u64 cur = tk[h];
    if(cur==code) return (long long)h;
    if(cur==KEMPTY) return -1;
    h=(h+1)&cmask;
  }
  return -1;
}

static __device__ __forceinline__ void atomAddF(float* p, float v){
#if defined(__gfx90a__) || defined(__gfx940__) || defined(__gfx941__) || defined(__gfx942__) || defined(__gfx950__)
  unsafeAtomicAdd(p, v);
#else
  atomicAdd(p, v);
#endif
}

static __device__ __forceinline__ void lds_add(float* p, float v){
  __hip_atomic_fetch_add(p, v, __ATOMIC_RELAXED, __HIP_MEMORY_SCOPE_WORKGROUP);
}
static __device__ __forceinline__ void lds_addu(u32* p, u32 v){
  __hip_atomic_fetch_add(p, v, __ATOMIC_RELAXED, __HIP_MEMORY_SCOPE_WORKGROUP);
}
static __device__ __forceinline__ u32 lds_addu_rtn(u32* p, u32 v){
  return __hip_atomic_fetch_add(p, v, __ATOMIC_RELAXED, __HIP_MEMORY_SCOPE_WORKGROUP);
}

static __device__ __forceinline__ void row_load(const float* __restrict__ p, float* o){
  const float4* q=(const float4*)p;
#pragma unroll
  for(int i=0;i<4;i++){ float4 v=q[i]; o[4*i]=v.x; o[4*i+1]=v.y; o[4*i+2]=v.z; o[4*i+3]=v.w; }
}
static __device__ __forceinline__ void row_store(float* __restrict__ p, const float* o){
  float4* q=(float4*)p;
#pragma unroll
  for(int i=0;i<4;i++) q[i]=make_float4(o[4*i],o[4*i+1],o[4*i+2],o[4*i+3]);
}

// ---------------- kernel 1: elevate/rank/bary + table insert; stores SLOT in inv ----------------
__global__ void __launch_bounds__(256)
k_setup(const float* __restrict__ feat, int N,
        u64* __restrict__ tabk, u32 cmask,
        u32* __restrict__ inv_slot, float* __restrict__ bary)
{
#pragma clang fp contract(off)
  int n = blockIdx.x*256 + threadIdx.x;
  if(n>=N) return;

  const float s0=3.4641016151377544f, s1=2.0f, s2=1.4142135623730951f,
              s3=1.0954451150103321f, s4=0.8944271909999159f;
  float c[5];
  c[0]=feat[n*5+0]*s0; c[1]=feat[n*5+1]*s1; c[2]=feat[n*5+2]*s2;
  c[3]=feat[n*5+3]*s3; c[4]=feat[n*5+4]*s4;

  float sfx[6]; sfx[5]=0.f;
#pragma unroll
  for(int i=4;i>=0;i--) sfx[i]=sfx[i+1]+c[i];
  float el[6];
  el[0]=sfx[0];
#pragma unroll
  for(int i=1;i<6;i++) el[i]=sfx[i]-(float)i*c[i-1];

  const float down=1.0f/6.0f;
  float rd[6], rem0[6], rdsum=0.f;
#pragma unroll
  for(int i=0;i<6;i++){ rd[i]=rintf(el[i]*down); rem0[i]=rd[i]*6.0f; rdsum+=rd[i]; }
  int sumi=(int)rdsum;

  float diff[6];
#pragma unroll
  for(int i=0;i<6;i++) diff[i]=(el[i]-rem0[i])*down;

  int rank[6];
#pragma unroll
  for(int i=0;i<6;i++){
    int r=0;
#pragma unroll
    for(int j=0;j<6;j++)
      r += (diff[j]>diff[i]) || (diff[j]==diff[i] && j<i);
    rank[i]=r+sumi;
  }
  int rem0i[6];
#pragma unroll
  for(int i=0;i<6;i++){
    rem0i[i]=(int)rem0[i];
    int sh=(rank[i]<0)-(rank[i]>5);
    rank[i]+=6*sh; rem0i[i]+=6*sh;
  }

  float b[7]={0.f,0.f,0.f,0.f,0.f,0.f,0.f};
#pragma unroll
  for(int i=0;i<6;i++){
    float t=(el[i]-(float)rem0i[i])*down;
    int k0=5-rank[i]; if(k0>=0&&k0<7) b[k0]+=t;
  }
#pragma unroll
  for(int i=0;i<6;i++){
    float t=(el[i]-(float)rem0i[i])*down;
    int k1=6-rank[i]; if(k1>=0&&k1<7) b[k1]-=t;
  }
  bary[(size_t)n*6+0]=(b[0]+1.0f)+b[6];
#pragma unroll
  for(int r=1;r<6;r++) bary[(size_t)n*6+r]=b[r];

#pragma unroll 1
  for(int r=0;r<6;r++){
    long long code=0;
#pragma unroll
    for(int i=0;i<5;i++){
      int key = rem0i[i] + ((rank[i] >= 6-r) ? (r-6) : r);
      code = code*2048 + (long long)(key+1024);
    }
    u32 h=(u32)mix64((u64)code)&cmask;
    u32 slot=0xFFFFFFFFu;
#pragma unroll 1
    for(int p=0;p<PROBE_CAP;p++){
      u64 cur=tabk[h];
      if(cur==(u64)code){ slot=h; break; }
      if(cur==KEMPTY){
        u64 old=atomicCAS((unsigned long long*)&tabk[h], KEMPTY, (u64)code);
        if(old==KEMPTY || old==(u64)code){ slot=h; break; }
      } else {
        h=(h+1)&cmask;
      }
    }
    inv_slot[(size_t)n*6+r]=slot;
  }
}

// ---------------- kernel 2: compact uids ----------------
__global__ void __launch_bounds__(256)
k_uid(const u64* __restrict__ tabk, u32 C, u32 Ucap, u32* __restrict__ tuid,
      u32* __restrict__ uidslot, u32* __restrict__ counter)
{
  u32 s=blockIdx.x*256+threadIdx.x;
  if(s>=C) return;
  if(tabk[s]==KEMPTY) return;
  u32 uid=atomicAdd(counter,1u);
  if(uid<Ucap) uidslot[uid]=s; else uid=0;
  tuid[s]=uid;
}

// ---------------- kernel 3: slot -> uid translation ----------------
__global__ void __launch_bounds__(256)
k_translate(u32* __restrict__ inv, const u32* __restrict__ tuid, size_t M)
{
  size_t i=(size_t)blockIdx.x*256+threadIdx.x;
  if(i<M) inv[i]=tuid[inv[i]];
}

// ================= TIER 1: single-pass 4-way channel-split splat (U <= U4CAP) =================
// 256 blocks (1/CU, 162.5KB static LDS). block j: cs=j&3 (channel quarter), sub=j>>2.
// Row stride 5 (gcd(5,32)=1 -> uniform banks). Every ds_add has full 64-lane exec mask;
// total ds_add instruction count = theoretical minimum (1.57M).
__global__ void __launch_bounds__(1024, 1)
k_saccum2(const u32* __restrict__ inv, const float* __restrict__ bary,
          const float* __restrict__ values, const u32* __restrict__ counter,
          int N, float* __restrict__ partial4)
{
  __shared__ float acc4[U4CAP*5];
  u32 U=*counter;
  if(U>U4CAP) return;
  u32 j=blockIdx.x;
  u32 cs=j&3, sub=j>>2;
  u32 t=threadIdx.x;
  for(u32 x=t;x<U*5;x+=1024) acc4[x]=0.f;
  __syncthreads();

  size_t p0=((size_t)sub*(size_t)N)/S4;
  size_t p1=((size_t)(sub+1)*(size_t)N)/S4;
  const float4* vbase=(const float4*)values;
  for(size_t i=p0+t;i<p1;i+=1024){
    const u32* ip=inv+i*6;
    const float* bp=bary+i*6;
    float4 va=vbase[i*4+cs];
#pragma unroll
    for(int r=0;r<6;r++){
      u32 a=ip[r]*5;
      float w=bp[r];
      lds_add(&acc4[a+0], w*va.x);
      lds_add(&acc4[a+1], w*va.y);
      lds_add(&acc4[a+2], w*va.z);
      lds_add(&acc4[a+3], w*va.w);
    }
  }
  __syncthreads();
  // compact flush: U*4 floats per block
  float* dst=partial4+(size_t)j*(U4CAP*4);
  for(u32 x=t;x<U*4;x+=1024) dst[x]=acc4[(x>>2)*5+(x&3)];
}

// sum the S4 sub-partials of each channel-set into v0
__global__ void __launch_bounds__(256)
k_reduce2(const float* __restrict__ partial4, const u32* __restrict__ counter,
          float* __restrict__ v0)
{
  u32 U=*counter;
  if(U>U4CAP) return;
  u32 e=blockIdx.x*256+threadIdx.x;
  u32 csz=U*4u;
  if(e>=4u*csz) return;
  u32 cs=e/csz; u32 rem=e-cs*csz;
  u32 u=rem>>2, k=rem&3;
  const float* base=partial4+(size_t)cs*(U4CAP*4)+rem;
  float s=0.f;
  for(u32 ss=0;ss<S4;ss++) s+=base[(size_t)ss*4u*(U4CAP*4)];
  v0[(size_t)u*16+cs*4+k]=s;
}

// ================= TIER 2: pass-based stream splat (U4CAP < U <= THRESH) =================
__global__ void __launch_bounds__(1024, 8)
k_saccum(const u32* __restrict__ inv, const float* __restrict__ bary,
         const float* __restrict__ values, const u32* __restrict__ counter,
         u32 Ucap, u32 loU, int N, float* __restrict__ partial)
{
  __shared__ float acc[RPP*17];
  u32 U=*counter; if(U>Ucap) U=Ucap;
  if(U<=loU || U>THRESH) return;
  u32 P=(U+RPP-1)/RPP;
  u32 S=TOTAL_B/P;
  u32 j=blockIdx.x;
  if(j>=P*S) return;
  u32 pass=j/S, sub=j-pass*S;
  u32 lo=pass*RPP;
  u32 t=threadIdx.x;
  for(u32 x=t;x<RPP*17;x+=1024) acc[x]=0.f;
  __syncthreads();

  size_t p0=((size_t)sub*(size_t)N)/S;
  size_t p1=((size_t)(sub+1)*(size_t)N)/S;
  for(size_t i=p0+t;i<p1;i+=1024){
    const u32* ip=inv+i*6;
    const float* bp=bary+i*6;
    u32 u[6]; float w[6];
#pragma unroll
    for(int r=0;r<6;r++){ u[r]=ip[r]-lo; w[r]=bp[r]; }
    bool any=false;
#pragma unroll
    for(int r=0;r<6;r++) any = any | (u[r]<RPP);
    if(!any) continue;
    float v[16];
    row_load(values+(size_t)i*16, v);
#pragma unroll
    for(int r=0;r<6;r++){
      if(u[r]<RPP){
        u32 a=u[r]*17; float ww=w[r];
#pragma unroll
        for(int k=0;k<16;k++) lds_add(&acc[a+k], ww*v[k]);
      }
    }
  }
  __syncthreads();
  float* dst=partial+(size_t)j*(RPP*17);
  for(u32 x=t;x<RPP*17;x+=1024) dst[x]=acc[x];
}

__global__ void __launch_bounds__(256)
k_reduce(const float* __restrict__ partial, const u32* __restrict__ counter,
         u32 Ucap, u32 loU, float* __restrict__ v0)
{
  u32 U=*counter; if(U>Ucap) U=Ucap;
  if(U<=loU || U>THRESH) return;
  u32 P=(U+RPP-1)/RPP, S=TOTAL_B/P;
  const u32 RG=RPP/16;
  u32 bid=blockIdx.x;
  u32 pass=bid/RG, rg=bid-pass*RG;
  if(pass>=P) return;
  u32 t=threadIdx.x;
  u32 r16=t>>4, k=t&15;
  u32 lrow=rg*16+r16;
  u32 gu=pass*RPP+lrow;
  const float* base=partial+((size_t)pass*S)*(RPP*17)+(size_t)lrow*17+k;
  float s=0.f;
  for(u32 ss=0;ss<S;ss++) s+=base[(size_t)ss*(RPP*17)];
  if(gu<U) v0[(size_t)gu*16+k]=s;
}

// ================= TIER 3: partition path (U > THRESH) =================
__global__ void __launch_bounds__(256)
k_hist(const u32* __restrict__ inv, const u32* __restrict__ counter,
       u32* __restrict__ hist, size_t M)
{
  if(*counter<=THRESH) return;
  __shared__ u32 h[BINS];
  u32 t=threadIdx.x, b=blockIdx.x;
#pragma unroll
  for(int j=0;j<(int)(BINS/256);j++) h[t+j*256]=0;
  __syncthreads();
  size_t base=(size_t)b*CHUNK;
#pragma unroll
  for(int j=0;j<(int)(CHUNK/256);j++){
    size_t i=base + (size_t)j*256 + t;
    if(i<M){
      u32 u=inv[i];
      lds_addu(&h[u&(BINS-1)],1u);
    }
  }
  __syncthreads();
#pragma unroll
  for(int j=0;j<(int)(BINS/256);j++){
    u32 bin=t+j*256;
    hist[(size_t)b*BINS+bin]=h[bin];
  }
}

__global__ void __launch_bounds__(256)
k_transpose(const u32* __restrict__ in, u32* __restrict__ out, u32 R, u32 C,
            const u32* __restrict__ counter)
{
  if(*counter<=THRESH) return;
  __shared__ u32 tile[32][33];
  u32 bx=blockIdx.x, by=blockIdx.y;
  u32 tx=threadIdx.x&31, ty=threadIdx.x>>5;
  u32 c0=bx*32, r0=by*32;
#pragma unroll
  for(u32 j=0;j<32;j+=8){
    u32 r=r0+ty+j, c=c0+tx;
    if(r<R && c<C) tile[ty+j][tx]=in[(size_t)r*C+c];
  }
  __syncthreads();
#pragma unroll
  for(u32 j=0;j<32;j+=8){
    u32 c=c0+ty+j, r=r0+tx;
    if(c<C && r<R) out[(size_t)c*R+r]=tile[tx][ty+j];
  }
}

__global__ void __launch_bounds__(256)
k_scan1(const u32* __restrict__ v, u32* __restrict__ bsum, const u32* __restrict__ counter)
{
  if(*counter<=THRESH) return;
  __shared__ u32 sm[256];
  u32 t=threadIdx.x, b=blockIdx.x;
  size_t base=((size_t)b*256+t)*4;
  u32 s=v[base]+v[base+1]+v[base+2]+v[base+3];
  sm[t]=s; __syncthreads();
  for(int o=128;o>0;o>>=1){ if(t<(u32)o) sm[t]+=sm[t+o]; __syncthreads(); }
  if(t==0) bsum[b]=sm[0];
}

__global__ void __launch_bounds__(256)
k_scan2(u32* __restrict__ bsum, u32 nb, const u32* __restrict__ counter)
{
  if(*counter<=THRESH) return;
  __shared__ u32 sm[256];
  u32 t=threadIdx.x;
  u32 per=(nb+255)/256;
  u32 lo=t*per, hi=lo+per; if(hi>nb) hi=nb; if(lo>nb) lo=nb;
  u32 tot=0;
  for(u32 i=lo;i<hi;i++) tot+=bsum[i];
  sm[t]=tot; __syncthreads();
  for(int o=1;o<256;o<<=1){
    u32 v=sm[t]; u32 a=(t>=(u32)o)?sm[t-o]:0u; __syncthreads();
    sm[t]=v+a; __syncthreads();
  }
  u32 run=sm[t]-tot;
  for(u32 i=lo;i<hi;i++){ u32 c=bsum[i]; bsum[i]=run; run+=c; }
}

__global__ void __launch_bounds__(256)
k_scan3(u32* __restrict__ v, const u32* __restrict__ bsum, const u32* __restrict__ counter)
{
  if(*counter<=THRESH) return;
  __shared__ u32 sm[256];
  u32 t=threadIdx.x, b=blockIdx.x;
  size_t base=((size_t)b*256+t)*4;
  u32 c[4]; u32 tot=0;
#pragma unroll
  for(int j=0;j<4;j++){ c[j]=v[base+j]; tot+=c[j]; }
  sm[t]=tot; __syncthreads();
  for(int o=1;o<256;o<<=1){
    u32 x=sm[t]; u32 a=(t>=(u32)o)?sm[t-o]:0u; __syncthreads();
    sm[t]=x+a; __syncthreads();
  }
  u32 run=bsum[b]+sm[t]-tot;
#pragma unroll
  for(int j=0;j<4;j++){ v[base+j]=run; run+=c[j]; }
}

__global__ void __launch_bounds__(256)
k_part(const u32* __restrict__ inv, const float* __restrict__ bary,
       const u32* __restrict__ histT, u32 nb,
       u32* __restrict__ skey, float* __restrict__ sw, size_t M,
       const u32* __restrict__ counter)
{
  if(*counter<=THRESH) return;
  __shared__ u32 cur[BINS];
  u32 t=threadIdx.x, b=blockIdx.x;
#pragma unroll
  for(int j=0;j<(int)(BINS/256);j++){
    u32 bin=t+j*256;
    cur[bin]=histT[(size_t)bin*nb+b];
  }
  __syncthreads();
  size_t base=(size_t)b*CHUNK;
#pragma unroll
  for(int j=0;j<(int)(CHUNK/256);j++){
    size_t i=base+(size_t)j*256+t;
    if(i<M){
      u32 u=inv[i];
      u32 pos=lds_addu_rtn(&cur[u&(BINS-1)],1u);
      skey[pos]=((u>>12)<<20)|((u32)(i/6u));
      sw[pos]=bary[i];
    }
  }
}

__global__ void __launch_bounds__(256)
k_queue(const u32* __restrict__ histT, u32 nb, size_t M,
        u32* __restrict__ q, u32* __restrict__ qn, const u32* __restrict__ counter)
{
  if(*counter<=THRESH) return;
  u32 b=blockIdx.x*256+threadIdx.x;
  if(b>=BINS) return;
  size_t s=histT[(size_t)b*nb];
  size_t e=(b+1<BINS)? (size_t)histT[(size_t)(b+1)*nb] : M;
  u32 sz=(u32)(e-s);
  if(sz==0) return;
  u32 G=(sz+SPLIT-1)/SPLIT; if(G>1023u) G=1023u;
  u32 base=atomicAdd(qn,G);
  for(u32 g=0; g<G; g++) q[base+g] = b | (g<<12) | (G<<22);
}

__global__ void __launch_bounds__(256)
k_accum(const u32* __restrict__ q, const u32* __restrict__ qn,
        const u32* __restrict__ skey, const float* __restrict__ sw,
        const float* __restrict__ values, const u32* __restrict__ histT,
        u32 nb, u32 rows, size_t M, float* __restrict__ v0)
{
  __shared__ float acc[4352];
  u32 j=blockIdx.x;
  if(j>=*qn) return;
  u32 ent=q[j];
  u32 b=ent&4095u, g=(ent>>12)&1023u, G=ent>>22;
  size_t s0=histT[(size_t)b*nb];
  size_t e0=(b+1<BINS)? (size_t)histT[(size_t)(b+1)*nb] : M;
  u32 sz=(u32)(e0-s0);
  u32 chunk=(sz+G-1)/G;
  size_t s=s0+(size_t)g*chunk;
  size_t e=s+chunk; if(e>e0) e=e0;

  u32 t=threadIdx.x;
  for(u32 x=t;x<rows*17;x+=256) acc[x]=0.f;
  __syncthreads();

  if(G==1){
    size_t base=s;
    for(; base+512<=e; base+=512){
      size_t i0=base+t, i1=base+256+t;
      u32 key0=skey[i0], key1=skey[i1];
      float w0=sw[i0], w1=sw[i1];
      float r0[16], r1[16];
      row_load(values+(size_t)(key0&0xFFFFFu)*16, r0);
      row_load(values+(size_t)(key1&0xFFFFFu)*16, r1);
      u32 a0=(key0>>20)*17, a1=(key1>>20)*17;
#pragma unroll
      for(int k=0;k<16;k++) lds_add(&acc[a0+k], w0*r0[k]);
#pragma unroll
      for(int k=0;k<16;k++) lds_add(&acc[a1+k], w1*r1[k]);
    }
    for(; base<e; base+=256){
      size_t ei=base+t;
      if(ei<e){
        u32 key=skey[ei]; float w=sw[ei];
        float r[16];
        row_load(values+(size_t)(key&0xFFFFFu)*16, r);
        u32 a=(key>>20)*17;
#pragma unroll
        for(int k=0;k<16;k++) lds_add(&acc[a+k], w*r[k]);
      }
    }
  } else {
    u32 gr=t>>4, k=t&15;
    size_t base=s;
    for(; base+128<=e; base+=128){
      u32 key[8]; float w[8]; float x[8];
#pragma unroll
      for(int u8=0;u8<8;u8++){ size_t ei=base+(size_t)u8*16+gr; key[u8]=skey[ei]; w[u8]=sw[ei]; }
#pragma unroll
      for(int u8=0;u8<8;u8++){ x[u8]=values[(size_t)(key[u8]&0xFFFFFu)*16+k]; }
#pragma unroll
      for(int u8=0;u8<8;u8++) lds_add(&acc[(key[u8]>>20)*17+k], w[u8]*x[u8]);
    }
    for(; base<e; base+=16){
      size_t ei=base+gr;
      if(ei<e){
        u32 key=skey[ei]; float w=sw[ei];
        float x=values[(size_t)(key&0xFFFFFu)*16+k];
        lds_add(&acc[(key>>20)*17+k], w*x);
      }
    }
  }
  __syncthreads();

  if(G==1){
    for(u32 x=t;x<rows*16;x+=256){
      u32 row=x>>4, kk=x&15;
      v0[(size_t)((row<<12)|b)*16+kk]=acc[row*17+kk];
    }
  } else {
    for(u32 x=t;x<rows*16;x+=256){
      u32 row=x>>4, kk=x&15;
      float a=acc[row*17+kk];
      if(a!=0.f) atomAddF(&v0[(size_t)((row<<12)|b)*16+kk], a);
    }
  }
}

// ---------------- blur ----------------
__global__ void __launch_bounds__(256)
k_blur(const u64* __restrict__ tabk, const u32* __restrict__ tuid, u32 cmask,
       const u32* __restrict__ uidslot, const u32* __restrict__ counter, u32 Ucap,
       long long delta, const float* __restrict__ vin, float* __restrict__ vout)
{
  u32 m=blockIdx.x*256+threadIdx.x;
  u32 U=*counter; if(U>Ucap) U=Ucap;
  if(m>=U) return;
  long long code=(long long)tabk[uidslot[m]];
  long long sp=lookup_slot(tabk,cmask,(u64)(code+delta));
  long long sm=lookup_slot(tabk,cmask,(u64)(code-delta));
  float acc[16];
  row_load(vin+(size_t)m*16, acc);
#pragma unroll
  for(int k=0;k<16;k++) acc[k]*=0.5f;
  if(sp>=0){
    u32 u=tuid[sp]; float t[16]; row_load(vin+(size_t)u*16,t);
#pragma unroll
    for(int k=0;k<16;k++) acc[k]+=0.25f*t[k];
  }
  if(sm>=0){
    u32 u=tuid[sm]; float t[16]; row_load(vin+(size_t)u*16,t);
#pragma unroll
    for(int k=0;k<16;k++) acc[k]+=0.25f*t[k];
  }
  row_store(vout+(size_t)m*16, acc);
}

// ---------------- slice ----------------
__global__ void __launch_bounds__(256)
k_slice(const u32* __restrict__ inv, const float* __restrict__ bary,
        const float* __restrict__ val, int N, float* __restrict__ out)
{
  int n=blockIdx.x*256+threadIdx.x;
  if(n>=N) return;
  u32 u[6]; float w[6];
#pragma unroll
  for(int r=0;r<6;r++){ u[r]=inv[(size_t)n*6+r]; w[r]=bary[(size_t)n*6+r]; }
  float t6[6][16];
#pragma unroll
  for(int r=0;r<6;r++) row_load(val+(size_t)u[r]*16, t6[r]);
  float acc[16];
#pragma unroll
  for(int k=0;k<16;k++){
    float a=w[0]*t6[0][k];
#pragma unroll
    for(int r=1;r<6;r++) a+=w[r]*t6[r][k];
    acc[k]=a;
  }
  const float alpha=0.9696969696969697f;
  float4* q=(float4*)(out+(size_t)n*16);
#pragma unroll
  for(int i=0;i<4;i++) q[i]=make_float4(alpha*acc[4*i],alpha*acc[4*i+1],alpha*acc[4*i+2],alpha*acc[4*i+3]);
}

__global__ void k_diag(float* out, float v){ out[0]=v; }

// ---------------- host ----------------
extern "C" void kernel_launch(void* const* d_in, const int* in_sizes, int n_in,
                              void* d_out, int out_size, void* d_ws, size_t ws_size,
                              hipStream_t stream)
{
  const float* feat   =(const float*)d_in[0];
  const float* values =(const float*)d_in[1];
  float* out=(float*)d_out;
  int N=in_sizes[0]/5;
  size_t M=(size_t)N*6;

  u32 nb=(u32)((M+CHUNK-1)/CHUNK);
  size_t K=(size_t)nb*BINS;
  const u32 QCAP=16384;

  // v1 union: partition scratch OR tier-2 partials OR tier-1 partials
  size_t partial_bytes =(size_t)TOTAL_B*(RPP*17)*4;          // 33.4 MB
  size_t partial4_bytes=(size_t)(4*S4)*(size_t)(U4CAP*4)*4;  // 33.3 MB
  auto v1bytes=[&](size_t U)->size_t{
    size_t a=U*64;
    size_t b=K*4+K*4+M*4+M*4+(K/1024)*4+QCAP*4+1024;
    size_t m1=a>b?a:b;
    if(partial_bytes>m1) m1=partial_bytes;
    if(partial4_bytes>m1) m1=partial4_bytes;
    return m1;
  };
  auto need=[&](int lC,int lU)->size_t{
    size_t C=1ull<<lC, U=1ull<<lU, s=0;
    auto al=[&](size_t b){ s=(s+255)&~(size_t)255; s+=b; };
    al(4); al(M*4); al(M*4); al(C*8); al(C*4); al(U*4); al(U*64); al(v1bytes(U));
    return s+256;
  };
  const int prefs[4][2]={{22,20},{21,20},{21,19},{20,18}};
  int lC=0,lU=0;
  for(int i=0;i<4;i++){ if(need(prefs[i][0],prefs[i][1])<=ws_size){ lC=prefs[i][0]; lU=prefs[i][1]; break; } }
  if(!lC){
    hipMemsetAsync(d_out,0,(size_t)out_size*sizeof(float),stream);
    k_diag<<<1,1,0,stream>>>(out,(float)(ws_size>>20));
    return;
  }

  size_t C=1ull<<lC, Ucap=1ull<<lU; u32 cmask=(u32)(C-1);
  char* base=(char*)d_ws; size_t offb=0;
  auto carve=[&](size_t b)->char*{ offb=(offb+255)&~(size_t)255; char* p=base+offb; offb+=b; return p; };
  u32*   counter=(u32*)carve(4);
  u32*   inv    =(u32*)carve(M*4);
  float* bary   =(float*)carve(M*4);
  u64*   tabk   =(u64*)carve(C*8);
  u32*   tuid   =(u32*)carve(C*4);
  u32*   uidslot=(u32*)carve(Ucap*4);
  float* v0     =(float*)carve(Ucap*64);
  float* v1     =(float*)carve(v1bytes(Ucap));

  u32*   hist =(u32*)v1;
  u32*   histT=hist+K;
  u32*   skey =histT+K;
  float* sw   =(float*)(skey+M);
  u32*   bsum =(u32*)(sw+M);
  u32*   q    =bsum+(K/1024);
  u32*   qn   =q+QCAP;
  float* partial =(float*)v1;   // tier-2 alias
  float* partial4=(float*)v1;   // tier-1 alias

  hipMemsetAsync(counter,0,4,stream);
  hipMemsetAsync(tabk,0xFF,C*8,stream);
  hipMemsetAsync(v0,0,Ucap*64,stream);

  const int B=256;
  k_setup    <<<(N+B-1)/B,B,0,stream>>>(feat,N,tabk,cmask,inv,bary);
  k_uid      <<<(u32)((C+B-1)/B),B,0,stream>>>(tabk,(u32)C,(u32)Ucap,tuid,uidslot,counter);
  k_translate<<<(u32)((M+B-1)/B),B,0,stream>>>(inv,tuid,M);

  // ---- tier 1: single-pass 4-way channel-split (dead unless U<=U4CAP) ----
  k_saccum2<<<4*S4,1024,0,stream>>>(inv,bary,values,counter,N,partial4);
  k_reduce2<<<(4*U4CAP*4+B-1)/B,B,0,stream>>>(partial4,counter,v0);

  // ---- tier 2: pass path (dead unless U4CAP < U <= THRESH) ----
  k_saccum<<<TOTAL_B,1024,0,stream>>>(inv,bary,values,counter,(u32)Ucap,U4CAP,N,partial);
  k_reduce<<<PMAX*(RPP/16),B,0,stream>>>(partial,counter,(u32)Ucap,U4CAP,v0);

  // ---- tier 3: partition path (dead unless U > THRESH) ----
  hipMemsetAsync(qn,0,4,stream);
  k_hist <<<nb,B,0,stream>>>(inv,counter,hist,M);
  {
    dim3 g((BINS+31)/32,(nb+31)/32);
    k_transpose<<<g,B,0,stream>>>(hist,histT,nb,BINS,counter);
  }
  u32 sb=(u32)(K/1024);
  k_scan1<<<sb,B,0,stream>>>(histT,bsum,counter);
  k_scan2<<<1 ,B,0,stream>>>(bsum,sb,counter);
  k_scan3<<<sb,B,0,stream>>>(histT,bsum,counter);
  k_part <<<nb,B,0,stream>>>(inv,bary,histT,nb,skey,sw,M,counter);
  k_queue<<<(BINS+B-1)/B,B,0,stream>>>(histT,nb,M,q,qn,counter);
  u32 rows=(u32)(Ucap>>12);
  k_accum<<<QCAP,B,0,stream>>>(q,qn,skey,sw,values,histT,nb,rows,M,v0);

  const long long P[5]={1ll,2048ll,1ll<<22,1ll<<33,1ll<<44};
  const long long SUM=P[0]+P[1]+P[2]+P[3]+P[4];
  u32 gb=(u32)((Ucap+B-1)/B);
  float* a=v0; float* bb=v1;
  for(int j=0;j<6;j++){
    long long delta=(j<5)? (SUM-6*P[4-j]) : SUM;
    k_blur<<<gb,B,0,stream>>>(tabk,tuid,cmask,uidslot,counter,(u32)Ucap,delta,a,bb);
    float* t=a; a=bb; bb=t;
  }
  k_slice<<<(N+B-1)/B,B,0,stream>>>(inv,bary,a,N,out);
}

// Round 15
// 1056.548 us; speedup vs baseline: 1.1960x; 1.1319x over previous
//
#include <hip/hip_runtime.h>
#include <stdint.h>

typedef unsigned long long u64;
typedef unsigned int u32;
typedef unsigned short u16;

static constexpr u64 KEMPTY = ~0ull;
static constexpr int PROBE_CAP = 32768;
static constexpr u32 BINS  = 4096;
static constexpr u32 CHUNK = 4096;
static constexpr u32 SPLIT = 2048;

static constexpr u32 THRESH = 23040;   // single-pass splat capacity == tier gate
static constexpr u32 UMAXR  = 23040;   // partial1 row stride
static constexpr u32 S1     = 16;      // point subranges (16 ch-sets x 16 = 256 blocks)

static __device__ __forceinline__ u64 mix64(u64 x){
  x ^= x >> 30; x *= 0xbf58476d1ce4e5b9ull;
  x ^= x >> 27; x *= 0x94d049bb133111ebull;
  x ^= x >> 31; return x;
}

static __device__ __forceinline__ long long lookup_slot(const u64* __restrict__ tk, u32 cmask, u64 code){
  u32 h = (u32)mix64(code) & cmask;
#pragma unroll 1
  for(int p=0;p<PROBE_CAP;p++){
    u64 cur = tk[h];
    if(cur==code) return (long long)h;
    if(cur==KEMPTY) return -1;
    h=(h+1)&cmask;
  }
  return -1;
}

static __device__ __forceinline__ void atomAddF(float* p, float v){
#if defined(__gfx90a__) || defined(__gfx940__) || defined(__gfx941__) || defined(__gfx942__) || defined(__gfx950__)
  unsafeAtomicAdd(p, v);
#else
  atomicAdd(p, v);
#endif
}

static __device__ __forceinline__ void lds_add(float* p, float v){
  __hip_atomic_fetch_add(p, v, __ATOMIC_RELAXED, __HIP_MEMORY_SCOPE_WORKGROUP);
}
static __device__ __forceinline__ void lds_addu(u32* p, u32 v){
  __hip_atomic_fetch_add(p, v, __ATOMIC_RELAXED, __HIP_MEMORY_SCOPE_WORKGROUP);
}
static __device__ __forceinline__ u32 lds_addu_rtn(u32* p, u32 v){
  return __hip_atomic_fetch_add(p, v, __ATOMIC_RELAXED, __HIP_MEMORY_SCOPE_WORKGROUP);
}

static __device__ __forceinline__ void row_load(const float* __restrict__ p, float* o){
  const float4* q=(const float4*)p;
#pragma unroll
  for(int i=0;i<4;i++){ float4 v=q[i]; o[4*i]=v.x; o[4*i+1]=v.y; o[4*i+2]=v.z; o[4*i+3]=v.w; }
}
static __device__ __forceinline__ void row_store(float* __restrict__ p, const float* o){
  float4* q=(float4*)p;
#pragma unroll
  for(int i=0;i<4;i++) q[i]=make_float4(o[4*i],o[4*i+1],o[4*i+2],o[4*i+3]);
}

// ---------------- kernel 1: elevate/rank/bary + table insert (PLANAR outputs) ----------------
__global__ void __launch_bounds__(256)
k_setup(const float* __restrict__ feat, int N,
        u64* __restrict__ tabk, u32 cmask,
        u32* __restrict__ inv_slot, float* __restrict__ baryT)
{
#pragma clang fp contract(off)
  int n = blockIdx.x*256 + threadIdx.x;
  if(n>=N) return;

  const float s0=3.4641016151377544f, s1=2.0f, s2=1.4142135623730951f,
              s3=1.0954451150103321f, s4=0.8944271909999159f;
  float c[5];
  c[0]=feat[n*5+0]*s0; c[1]=feat[n*5+1]*s1; c[2]=feat[n*5+2]*s2;
  c[3]=feat[n*5+3]*s3; c[4]=feat[n*5+4]*s4;

  float sfx[6]; sfx[5]=0.f;
#pragma unroll
  for(int i=4;i>=0;i--) sfx[i]=sfx[i+1]+c[i];
  float el[6];
  el[0]=sfx[0];
#pragma unroll
  for(int i=1;i<6;i++) el[i]=sfx[i]-(float)i*c[i-1];

  const float down=1.0f/6.0f;
  float rd[6], rem0[6], rdsum=0.f;
#pragma unroll
  for(int i=0;i<6;i++){ rd[i]=rintf(el[i]*down); rem0[i]=rd[i]*6.0f; rdsum+=rd[i]; }
  int sumi=(int)rdsum;

  float diff[6];
#pragma unroll
  for(int i=0;i<6;i++) diff[i]=(el[i]-rem0[i])*down;

  int rank[6];
#pragma unroll
  for(int i=0;i<6;i++){
    int r=0;
#pragma unroll
    for(int j=0;j<6;j++)
      r += (diff[j]>diff[i]) || (diff[j]==diff[i] && j<i);
    rank[i]=r+sumi;
  }
  int rem0i[6];
#pragma unroll
  for(int i=0;i<6;i++){
    rem0i[i]=(int)rem0[i];
    int sh=(rank[i]<0)-(rank[i]>5);
    rank[i]+=6*sh; rem0i[i]+=6*sh;
  }

  float b[7]={0.f,0.f,0.f,0.f,0.f,0.f,0.f};
#pragma unroll
  for(int i=0;i<6;i++){
    float t=(el[i]-(float)rem0i[i])*down;
    int k0=5-rank[i]; if(k0>=0&&k0<7) b[k0]+=t;
  }
#pragma unroll
  for(int i=0;i<6;i++){
    float t=(el[i]-(float)rem0i[i])*down;
    int k1=6-rank[i]; if(k1>=0&&k1<7) b[k1]-=t;
  }
  baryT[n]=(b[0]+1.0f)+b[6];
#pragma unroll
  for(int r=1;r<6;r++) baryT[(size_t)r*N+n]=b[r];

#pragma unroll 1
  for(int r=0;r<6;r++){
    long long code=0;
#pragma unroll
    for(int i=0;i<5;i++){
      int key = rem0i[i] + ((rank[i] >= 6-r) ? (r-6) : r);
      code = code*2048 + (long long)(key+1024);
    }
    u32 h=(u32)mix64((u64)code)&cmask;
    u32 slot=0xFFFFFFFFu;
#pragma unroll 1
    for(int p=0;p<PROBE_CAP;p++){
      u64 cur=tabk[h];
      if(cur==(u64)code){ slot=h; break; }
      if(cur==KEMPTY){
        u64 old=atomicCAS((unsigned long long*)&tabk[h], KEMPTY, (u64)code);
        if(old==KEMPTY || old==(u64)code){ slot=h; break; }
      } else {
        h=(h+1)&cmask;
      }
    }
    inv_slot[(size_t)r*N+n]=slot;
  }
}

// ---------------- kernel 2: compact uids ----------------
__global__ void __launch_bounds__(256)
k_uid(const u64* __restrict__ tabk, u32 C, u32 Ucap, u32* __restrict__ tuid,
      u32* __restrict__ uidslot, u32* __restrict__ counter)
{
  u32 s=blockIdx.x*256+threadIdx.x;
  if(s>=C) return;
  if(tabk[s]==KEMPTY) return;
  u32 uid=atomicAdd(counter,1u);
  if(uid<Ucap) uidslot[uid]=s; else uid=0;
  tuid[s]=uid;
}

// ---------------- kernel 3: slot -> uid translation + u16 mirror ----------------
__global__ void __launch_bounds__(256)
k_translate(u32* __restrict__ inv, u16* __restrict__ inv16,
            const u32* __restrict__ tuid, size_t M)
{
  size_t i=(size_t)blockIdx.x*256+threadIdx.x;
  if(i<M){
    u32 u=tuid[inv[i]];
    inv[i]=u;
    inv16[i]=(u16)u;   // valid only when U<65536 (single-pass path gate U<=23040)
  }
}

// ---------------- values transpose: [N][16] -> valuesT[16][N] ----------------
__global__ void __launch_bounds__(256)
k_vtrans(const float* __restrict__ values, float* __restrict__ valuesT, int N)
{
  __shared__ float tile[256][17];
  u32 b=blockIdx.x, t=threadIdx.x;
  size_t p=(size_t)b*256+t;
  float v[16];
  row_load(values+p*16, v);
#pragma unroll
  for(int k=0;k<16;k++) tile[t][k]=v[k];
  __syncthreads();
  u32 ch=t>>4, lane=t&15;
#pragma unroll
  for(int q=0;q<16;q++){
    u32 pt=q*16+lane;
    valuesT[(size_t)ch*N + (size_t)b*256 + pt]=tile[pt][ch];
  }
}

// ================= SINGLE-PASS 1-CHANNEL SPLAT (U <= THRESH) =================
// 256 blocks (1/CU, 92KB LDS, 16 waves). block j: cs=j&15 (channel), sub=j>>4.
// All streams coalesced planar; 6 full-exec-mask ds_add per point-visit ->
// 1.57M total LDS-atomic instructions (theoretical minimum).
__global__ void __launch_bounds__(1024, 1)
k_saccum1(const u16* __restrict__ inv16, const float* __restrict__ baryT,
          const float* __restrict__ valuesT, const u32* __restrict__ counter,
          int N, float* __restrict__ partial1)
{
  __shared__ float acc1[THRESH];   // 92160 B
  u32 U=*counter;
  if(U>THRESH) return;
  u32 j=blockIdx.x;
  u32 cs=j&15, sub=j>>4;
  u32 t=threadIdx.x;
  for(u32 x=t;x<U;x+=1024) acc1[x]=0.f;
  __syncthreads();

  u32 nsub=(u32)N/S1;                 // 65536
  size_t p0=(size_t)sub*nsub;
  const float* vch=valuesT+(size_t)cs*N;
  for(u32 i=t;i<nsub;i+=1024){
    size_t p=p0+i;
    float v=vch[p];
#pragma unroll
    for(int r=0;r<6;r++){
      u32 u=inv16[(size_t)r*N+p];
      float w=baryT[(size_t)r*N+p];
      lds_add(&acc1[u], w*v);
    }
  }
  __syncthreads();
  float* dst=partial1+(size_t)j*UMAXR;
  for(u32 x=t;x<U;x+=1024) dst[x]=acc1[x];
}

// sum the 16 sub-partials of each channel into v0
__global__ void __launch_bounds__(256)
k_reduce1(const float* __restrict__ partial1, const u32* __restrict__ counter,
          float* __restrict__ v0)
{
  u32 U=*counter;
  if(U>THRESH) return;
  u32 cs=blockIdx.y;
  u32 u=blockIdx.x*256+threadIdx.x;
  if(u>=U) return;
  float s=0.f;
#pragma unroll
  for(u32 sub=0;sub<S1;sub++)
    s+=partial1[(size_t)(sub*16+cs)*UMAXR+u];
  v0[(size_t)u*16+cs]=s;
}

// ================= PARTITION PATH (U > THRESH) =================
__global__ void __launch_bounds__(256)
k_hist(const u32* __restrict__ inv, const u32* __restrict__ counter,
       u32* __restrict__ hist, size_t M)
{
  if(*counter<=THRESH) return;
  __shared__ u32 h[BINS];
  u32 t=threadIdx.x, b=blockIdx.x;
#pragma unroll
  for(int j=0;j<(int)(BINS/256);j++) h[t+j*256]=0;
  __syncthreads();
  size_t base=(size_t)b*CHUNK;
#pragma unroll
  for(int j=0;j<(int)(CHUNK/256);j++){
    size_t i=base + (size_t)j*256 + t;
    if(i<M){
      u32 u=inv[i];
      lds_addu(&h[u&(BINS-1)],1u);
    }
  }
  __syncthreads();
#pragma unroll
  for(int j=0;j<(int)(BINS/256);j++){
    u32 bin=t+j*256;
    hist[(size_t)b*BINS+bin]=h[bin];
  }
}

__global__ void __launch_bounds__(256)
k_transpose(const u32* __restrict__ in, u32* __restrict__ out, u32 R, u32 C,
            const u32* __restrict__ counter)
{
  if(*counter<=THRESH) return;
  __shared__ u32 tile[32][33];
  u32 bx=blockIdx.x, by=blockIdx.y;
  u32 tx=threadIdx.x&31, ty=threadIdx.x>>5;
  u32 c0=bx*32, r0=by*32;
#pragma unroll
  for(u32 j=0;j<32;j+=8){
    u32 r=r0+ty+j, c=c0+tx;
    if(r<R && c<C) tile[ty+j][tx]=in[(size_t)r*C+c];
  }
  __syncthreads();
#pragma unroll
  for(u32 j=0;j<32;j+=8){
    u32 c=c0+ty+j, r=r0+tx;
    if(c<C && r<R) out[(size_t)c*R+r]=tile[tx][ty+j];
  }
}

__global__ void __launch_bounds__(256)
k_scan1(const u32* __restrict__ v, u32* __restrict__ bsum, const u32* __restrict__ counter)
{
  if(*counter<=THRESH) return;
  __shared__ u32 sm[256];
  u32 t=threadIdx.x, b=blockIdx.x;
  size_t base=((size_t)b*256+t)*4;
  u32 s=v[base]+v[base+1]+v[base+2]+v[base+3];
  sm[t]=s; __syncthreads();
  for(int o=128;o>0;o>>=1){ if(t<(u32)o) sm[t]+=sm[t+o]; __syncthreads(); }
  if(t==0) bsum[b]=sm[0];
}

__global__ void __launch_bounds__(256)
k_scan2(u32* __restrict__ bsum, u32 nb, const u32* __restrict__ counter)
{
  if(*counter<=THRESH) return;
  __shared__ u32 sm[256];
  u32 t=threadIdx.x;
  u32 per=(nb+255)/256;
  u32 lo=t*per, hi=lo+per; if(hi>nb) hi=nb; if(lo>nb) lo=nb;
  u32 tot=0;
  for(u32 i=lo;i<hi;i++) tot+=bsum[i];
  sm[t]=tot; __syncthreads();
  for(int o=1;o<256;o<<=1){
    u32 v=sm[t]; u32 a=(t>=(u32)o)?sm[t-o]:0u; __syncthreads();
    sm[t]=v+a; __syncthreads();
  }
  u32 run=sm[t]-tot;
  for(u32 i=lo;i<hi;i++){ u32 c=bsum[i]; bsum[i]=run; run+=c; }
}

__global__ void __launch_bounds__(256)
k_scan3(u32* __restrict__ v, const u32* __restrict__ bsum, const u32* __restrict__ counter)
{
  if(*counter<=THRESH) return;
  __shared__ u32 sm[256];
  u32 t=threadIdx.x, b=blockIdx.x;
  size_t base=((size_t)b*256+t)*4;
  u32 c[4]; u32 tot=0;
#pragma unroll
  for(int j=0;j<4;j++){ c[j]=v[base+j]; tot+=c[j]; }
  sm[t]=tot; __syncthreads();
  for(int o=1;o<256;o<<=1){
    u32 x=sm[t]; u32 a=(t>=(u32)o)?sm[t-o]:0u; __syncthreads();
    sm[t]=x+a; __syncthreads();
  }
  u32 run=bsum[b]+sm[t]-tot;
#pragma unroll
  for(int j=0;j<4;j++){ v[base+j]=run; run+=c[j]; }
}

__global__ void __launch_bounds__(256)
k_part(const u32* __restrict__ inv, const float* __restrict__ baryT,
       const u32* __restrict__ histT, u32 nb,
       u32* __restrict__ skey, float* __restrict__ sw, size_t M, u32 nmask,
       const u32* __restrict__ counter)
{
  if(*counter<=THRESH) return;
  __shared__ u32 cur[BINS];
  u32 t=threadIdx.x, b=blockIdx.x;
#pragma unroll
  for(int j=0;j<(int)(BINS/256);j++){
    u32 bin=t+j*256;
    cur[bin]=histT[(size_t)bin*nb+b];
  }
  __syncthreads();
  size_t base=(size_t)b*CHUNK;
#pragma unroll
  for(int j=0;j<(int)(CHUNK/256);j++){
    size_t i=base+(size_t)j*256+t;
    if(i<M){
      u32 u=inv[i];
      u32 pos=lds_addu_rtn(&cur[u&(BINS-1)],1u);
      skey[pos]=((u>>12)<<20)|((u32)i & nmask);
      sw[pos]=baryT[i];
    }
  }
}

__global__ void __launch_bounds__(256)
k_queue(const u32* __restrict__ histT, u32 nb, size_t M,
        u32* __restrict__ q, u32* __restrict__ qn, const u32* __restrict__ counter)
{
  if(*counter<=THRESH) return;
  u32 b=blockIdx.x*256+threadIdx.x;
  if(b>=BINS) return;
  size_t s=histT[(size_t)b*nb];
  size_t e=(b+1<BINS)? (size_t)histT[(size_t)(b+1)*nb] : M;
  u32 sz=(u32)(e-s);
  if(sz==0) return;
  u32 G=(sz+SPLIT-1)/SPLIT; if(G>1023u) G=1023u;
  u32 base=atomicAdd(qn,G);
  for(u32 g=0; g<G; g++) q[base+g] = b | (g<<12) | (G<<22);
}

__global__ void __launch_bounds__(256)
k_accum(const u32* __restrict__ q, const u32* __restrict__ qn,
        const u32* __restrict__ skey, const float* __restrict__ sw,
        const float* __restrict__ values, const u32* __restrict__ histT,
        u32 nb, u32 rows, size_t M, float* __restrict__ v0)
{
  __shared__ float acc[4352];
  u32 j=blockIdx.x;
  if(j>=*qn) return;
  u32 ent=q[j];
  u32 b=ent&4095u, g=(ent>>12)&1023u, G=ent>>22;
  size_t s0=histT[(size_t)b*nb];
  size_t e0=(b+1<BINS)? (size_t)histT[(size_t)(b+1)*nb] : M;
  u32 sz=(u32)(e0-s0);
  u32 chunk=(sz+G-1)/G;
  size_t s=s0+(size_t)g*chunk;
  size_t e=s+chunk; if(e>e0) e=e0;

  u32 t=threadIdx.x;
  for(u32 x=t;x<rows*17;x+=256) acc[x]=0.f;
  __syncthreads();

  if(G==1){
    size_t base=s;
    for(; base+512<=e; base+=512){
      size_t i0=base+t, i1=base+256+t;
      u32 key0=skey[i0], key1=skey[i1];
      float w0=sw[i0], w1=sw[i1];
      float r0[16], r1[16];
      row_load(values+(size_t)(key0&0xFFFFFu)*16, r0);
      row_load(values+(size_t)(key1&0xFFFFFu)*16, r1);
      u32 a0=(key0>>20)*17, a1=(key1>>20)*17;
#pragma unroll
      for(int k=0;k<16;k++) lds_add(&acc[a0+k], w0*r0[k]);
#pragma unroll
      for(int k=0;k<16;k++) lds_add(&acc[a1+k], w1*r1[k]);
    }
    for(; base<e; base+=256){
      size_t ei=base+t;
      if(ei<e){
        u32 key=skey[ei]; float w=sw[ei];
        float r[16];
        row_load(values+(size_t)(key&0xFFFFFu)*16, r);
        u32 a=(key>>20)*17;
#pragma unroll
        for(int k=0;k<16;k++) lds_add(&acc[a+k], w*r[k]);
      }
    }
  } else {
    u32 gr=t>>4, k=t&15;
    size_t base=s;
    for(; base+128<=e; base+=128){
      u32 key[8]; float w[8]; float x[8];
#pragma unroll
      for(int u8=0;u8<8;u8++){ size_t ei=base+(size_t)u8*16+gr; key[u8]=skey[ei]; w[u8]=sw[ei]; }
#pragma unroll
      for(int u8=0;u8<8;u8++){ x[u8]=values[(size_t)(key[u8]&0xFFFFFu)*16+k]; }
#pragma unroll
      for(int u8=0;u8<8;u8++) lds_add(&acc[(key[u8]>>20)*17+k], w[u8]*x[u8]);
    }
    for(; base<e; base+=16){
      size_t ei=base+gr;
      if(ei<e){
        u32 key=skey[ei]; float w=sw[ei];
        float x=values[(size_t)(key&0xFFFFFu)*16+k];
        lds_add(&acc[(key>>20)*17+k], w*x);
      }
    }
  }
  __syncthreads();

  if(G==1){
    for(u32 x=t;x<rows*16;x+=256){
      u32 row=x>>4, kk=x&15;
      v0[(size_t)((row<<12)|b)*16+kk]=acc[row*17+kk];
    }
  } else {
    for(u32 x=t;x<rows*16;x+=256){
      u32 row=x>>4, kk=x&15;
      float a=acc[row*17+kk];
      if(a!=0.f) atomAddF(&v0[(size_t)((row<<12)|b)*16+kk], a);
    }
  }
}

// ---------------- blur ----------------
__global__ void __launch_bounds__(256)
k_blur(const u64* __restrict__ tabk, const u32* __restrict__ tuid, u32 cmask,
       const u32* __restrict__ uidslot, const u32* __restrict__ counter, u32 Ucap,
       long long delta, const float* __restrict__ vin, float* __restrict__ vout)
{
  u32 m=blockIdx.x*256+threadIdx.x;
  u32 U=*counter; if(U>Ucap) U=Ucap;
  if(m>=U) return;
  long long code=(long long)tabk[uidslot[m]];
  long long sp=lookup_slot(tabk,cmask,(u64)(code+delta));
  long long sm=lookup_slot(tabk,cmask,(u64)(code-delta));
  float acc[16];
  row_load(vin+(size_t)m*16, acc);
#pragma unroll
  for(int k=0;k<16;k++) acc[k]*=0.5f;
  if(sp>=0){
    u32 u=tuid[sp]; float t[16]; row_load(vin+(size_t)u*16,t);
#pragma unroll
    for(int k=0;k<16;k++) acc[k]+=0.25f*t[k];
  }
  if(sm>=0){
    u32 u=tuid[sm]; float t[16]; row_load(vin+(size_t)u*16,t);
#pragma unroll
    for(int k=0;k<16;k++) acc[k]+=0.25f*t[k];
  }
  row_store(vout+(size_t)m*16, acc);
}

// ---------------- slice (planar inv/bary) ----------------
__global__ void __launch_bounds__(256)
k_slice(const u32* __restrict__ inv, const float* __restrict__ baryT,
        const float* __restrict__ val, int N, float* __restrict__ out)
{
  int n=blockIdx.x*256+threadIdx.x;
  if(n>=N) return;
  u32 u[6]; float w[6];
#pragma unroll
  for(int r=0;r<6;r++){ u[r]=inv[(size_t)r*N+n]; w[r]=baryT[(size_t)r*N+n]; }
  float t6[6][16];
#pragma unroll
  for(int r=0;r<6;r++) row_load(val+(size_t)u[r]*16, t6[r]);
  float acc[16];
#pragma unroll
  for(int k=0;k<16;k++){
    float a=w[0]*t6[0][k];
#pragma unroll
    for(int r=1;r<6;r++) a+=w[r]*t6[r][k];
    acc[k]=a;
  }
  const float alpha=0.9696969696969697f;
  float4* q=(float4*)(out+(size_t)n*16);
#pragma unroll
  for(int i=0;i<4;i++) q[i]=make_float4(alpha*acc[4*i],alpha*acc[4*i+1],alpha*acc[4*i+2],alpha*acc[4*i+3]);
}

__global__ void k_diag(float* out, float v){ out[0]=v; }

// ---------------- host ----------------
extern "C" void kernel_launch(void* const* d_in, const int* in_sizes, int n_in,
                              void* d_out, int out_size, void* d_ws, size_t ws_size,
                              hipStream_t stream)
{
  const float* feat   =(const float*)d_in[0];
  const float* values =(const float*)d_in[1];
  float* out=(float*)d_out;
  int N=in_sizes[0]/5;          // 2^20
  size_t M=(size_t)N*6;
  u32 nmask=(u32)(N-1);

  u32 nb=(u32)((M+CHUNK-1)/CHUNK);
  size_t K=(size_t)nb*BINS;
  const u32 QCAP=16384;

  // v1 union: partition scratch OR (valuesT + partial1) OR blur pingpong
  size_t part_scratch = K*4+K*4+M*4+M*4+(K/1024)*4+QCAP*4+1024;
  size_t vt_bytes     = (size_t)N*16*4;                    // 67.1 MB
  size_t partial1b    = (size_t)256*UMAXR*4;               // 23.6 MB
  auto v1bytes=[&](size_t U)->size_t{
    size_t m1=U*64;
    if(part_scratch>m1) m1=part_scratch;
    if(vt_bytes+partial1b>m1) m1=vt_bytes+partial1b;
    return m1;
  };
  auto need=[&](int lC,int lU)->size_t{
    size_t C=1ull<<lC, U=1ull<<lU, s=0;
    auto al=[&](size_t b){ s=(s+255)&~(size_t)255; s+=b; };
    al(4); al(M*4); al(M*4); al(M*2); al(C*8); al(C*4); al(U*4); al(U*64); al(v1bytes(U));
    return s+256;
  };
  const int prefs[3][2]={{21,20},{21,19},{20,18}};
  int lC=0,lU=0;
  for(int i=0;i<3;i++){ if(need(prefs[i][0],prefs[i][1])<=ws_size){ lC=prefs[i][0]; lU=prefs[i][1]; break; } }
  if(!lC){
    hipMemsetAsync(d_out,0,(size_t)out_size*sizeof(float),stream);
    k_diag<<<1,1,0,stream>>>(out,(float)(ws_size>>20));
    return;
  }

  size_t C=1ull<<lC, Ucap=1ull<<lU; u32 cmask=(u32)(C-1);
  char* base=(char*)d_ws; size_t offb=0;
  auto carve=[&](size_t b)->char*{ offb=(offb+255)&~(size_t)255; char* p=base+offb; offb+=b; return p; };
  u32*   counter=(u32*)carve(4);
  u32*   inv    =(u32*)carve(M*4);
  float* baryT  =(float*)carve(M*4);
  u16*   inv16  =(u16*)carve(M*2);
  u64*   tabk   =(u64*)carve(C*8);
  u32*   tuid   =(u32*)carve(C*4);
  u32*   uidslot=(u32*)carve(Ucap*4);
  float* v0     =(float*)carve(Ucap*64);
  float* v1     =(float*)carve(v1bytes(Ucap));

  // partition aliases
  u32*   hist =(u32*)v1;
  u32*   histT=hist+K;
  u32*   skey =histT+K;
  float* sw   =(float*)(skey+M);
  u32*   bsum =(u32*)(sw+M);
  u32*   q    =bsum+(K/1024);
  u32*   qn   =q+QCAP;
  // single-pass aliases
  float* valuesT =(float*)v1;
  float* partial1=(float*)((char*)v1+vt_bytes);

  hipMemsetAsync(counter,0,4,stream);
  hipMemsetAsync(tabk,0xFF,C*8,stream);
  hipMemsetAsync(v0,0,Ucap*64,stream);

  const int B=256;
  k_setup    <<<(N+B-1)/B,B,0,stream>>>(feat,N,tabk,cmask,inv,baryT);
  k_uid      <<<(u32)((C+B-1)/B),B,0,stream>>>(tabk,(u32)C,(u32)Ucap,tuid,uidslot,counter);
  k_translate<<<(u32)((M+B-1)/B),B,0,stream>>>(inv,inv16,tuid,M);

  // ---- single-pass splat (dead unless U<=23040) ----
  k_vtrans <<<(u32)(N/256),B,0,stream>>>(values,valuesT,N);
  k_saccum1<<<16*S1,1024,0,stream>>>(inv16,baryT,valuesT,counter,N,partial1);
  {
    dim3 g((THRESH+B-1)/B,16);
    k_reduce1<<<g,B,0,stream>>>(partial1,counter,v0);
  }

  // ---- partition path (dead unless U > 23040) ----
  hipMemsetAsync(qn,0,4,stream);
  k_hist <<<nb,B,0,stream>>>(inv,counter,hist,M);
  {
    dim3 g((BINS+31)/32,(nb+31)/32);
    k_transpose<<<g,B,0,stream>>>(hist,histT,nb,BINS,counter);
  }
  u32 sb=(u32)(K/1024);
  k_scan1<<<sb,B,0,stream>>>(histT,bsum,counter);
  k_scan2<<<1 ,B,0,stream>>>(bsum,sb,counter);
  k_scan3<<<sb,B,0,stream>>>(histT,bsum,counter);
  k_part <<<nb,B,0,stream>>>(inv,baryT,histT,nb,skey,sw,M,nmask,counter);
  k_queue<<<(BINS+B-1)/B,B,0,stream>>>(histT,nb,M,q,qn,counter);
  u32 rows=(u32)(Ucap>>12);
  k_accum<<<QCAP,B,0,stream>>>(q,qn,skey,sw,values,histT,nb,rows,M,v0);

  const long long P[5]={1ll,2048ll,1ll<<22,1ll<<33,1ll<<44};
  const long long SUM=P[0]+P[1]+P[2]+P[3]+P[4];
  u32 gb=(u32)((Ucap+B-1)/B);
  float* a=v0; float* bb=v1;
  for(int j=0;j<6;j++){
    long long delta=(j<5)? (SUM-6*P[4-j]) : SUM;
    k_blur<<<gb,B,0,stream>>>(tabk,tuid,cmask,uidslot,counter,(u32)Ucap,delta,a,bb);
    float* t=a; a=bb; bb=t;
  }
  k_slice<<<(N+B-1)/B,B,0,stream>>>(inv,baryT,a,N,out);
}

// Round 16
// 1055.577 us; speedup vs baseline: 1.1971x; 1.0009x over previous
//
#include <hip/hip_runtime.h>
#include <stdint.h>

typedef unsigned long long u64;
typedef unsigned int u32;
typedef unsigned short u16;

static constexpr u64 KEMPTY = ~0ull;
static constexpr int PROBE_CAP = 32768;
static constexpr u32 BINS  = 4096;
static constexpr u32 CHUNK = 4096;
static constexpr u32 SPLIT = 2048;

static constexpr u32 THRESH = 23040;   // single-pass splat capacity == tier gate
static constexpr u32 UMAXR  = 23040;   // partial1 row stride
static constexpr u32 S1     = 16;      // point subranges (16 ch-sets x 16 = 256 blocks)
static constexpr u32 R2CAP  = 20320;   // replicated-accumulator capacity (2*20320*4 = 162560 B)

static __device__ __forceinline__ u64 mix64(u64 x){
  x ^= x >> 30; x *= 0xbf58476d1ce4e5b9ull;
  x ^= x >> 27; x *= 0x94d049bb133111ebull;
  x ^= x >> 31; return x;
}

static __device__ __forceinline__ long long lookup_slot(const u64* __restrict__ tk, u32 cmask, u64 code){
  u32 h = (u32)mix64(code) & cmask;
#pragma unroll 1
  for(int p=0;p<PROBE_CAP;p++){
    u64 cur = tk[h];
    if(cur==code) return (long long)h;
    if(cur==KEMPTY) return -1;
    h=(h+1)&cmask;
  }
  return -1;
}

static __device__ __forceinline__ void atomAddF(float* p, float v){
#if defined(__gfx90a__) || defined(__gfx940__) || defined(__gfx941__) || defined(__gfx942__) || defined(__gfx950__)
  unsafeAtomicAdd(p, v);
#else
  atomicAdd(p, v);
#endif
}

static __device__ __forceinline__ void lds_add(float* p, float v){
  __hip_atomic_fetch_add(p, v, __ATOMIC_RELAXED, __HIP_MEMORY_SCOPE_WORKGROUP);
}
static __device__ __forceinline__ void lds_addu(u32* p, u32 v){
  __hip_atomic_fetch_add(p, v, __ATOMIC_RELAXED, __HIP_MEMORY_SCOPE_WORKGROUP);
}
static __device__ __forceinline__ u32 lds_addu_rtn(u32* p, u32 v){
  return __hip_atomic_fetch_add(p, v, __ATOMIC_RELAXED, __HIP_MEMORY_SCOPE_WORKGROUP);
}

static __device__ __forceinline__ void row_load(const float* __restrict__ p, float* o){
  const float4* q=(const float4*)p;
#pragma unroll
  for(int i=0;i<4;i++){ float4 v=q[i]; o[4*i]=v.x; o[4*i+1]=v.y; o[4*i+2]=v.z; o[4*i+3]=v.w; }
}
static __device__ __forceinline__ void row_store(float* __restrict__ p, const float* o){
  float4* q=(float4*)p;
#pragma unroll
  for(int i=0;i<4;i++) q[i]=make_float4(o[4*i],o[4*i+1],o[4*i+2],o[4*i+3]);
}

// ---------------- kernel 1: elevate/rank/bary + table insert (PLANAR outputs) ----------------
__global__ void __launch_bounds__(256)
k_setup(const float* __restrict__ feat, int N,
        u64* __restrict__ tabk, u32 cmask,
        u32* __restrict__ inv_slot, float* __restrict__ baryT)
{
#pragma clang fp contract(off)
  int n = blockIdx.x*256 + threadIdx.x;
  if(n>=N) return;

  const float s0=3.4641016151377544f, s1=2.0f, s2=1.4142135623730951f,
              s3=1.0954451150103321f, s4=0.8944271909999159f;
  float c[5];
  c[0]=feat[n*5+0]*s0; c[1]=feat[n*5+1]*s1; c[2]=feat[n*5+2]*s2;
  c[3]=feat[n*5+3]*s3; c[4]=feat[n*5+4]*s4;

  float sfx[6]; sfx[5]=0.f;
#pragma unroll
  for(int i=4;i>=0;i--) sfx[i]=sfx[i+1]+c[i];
  float el[6];
  el[0]=sfx[0];
#pragma unroll
  for(int i=1;i<6;i++) el[i]=sfx[i]-(float)i*c[i-1];

  const float down=1.0f/6.0f;
  float rd[6], rem0[6], rdsum=0.f;
#pragma unroll
  for(int i=0;i<6;i++){ rd[i]=rintf(el[i]*down); rem0[i]=rd[i]*6.0f; rdsum+=rd[i]; }
  int sumi=(int)rdsum;

  float diff[6];
#pragma unroll
  for(int i=0;i<6;i++) diff[i]=(el[i]-rem0[i])*down;

  int rank[6];
#pragma unroll
  for(int i=0;i<6;i++){
    int r=0;
#pragma unroll
    for(int j=0;j<6;j++)
      r += (diff[j]>diff[i]) || (diff[j]==diff[i] && j<i);
    rank[i]=r+sumi;
  }
  int rem0i[6];
#pragma unroll
  for(int i=0;i<6;i++){
    rem0i[i]=(int)rem0[i];
    int sh=(rank[i]<0)-(rank[i]>5);
    rank[i]+=6*sh; rem0i[i]+=6*sh;
  }

  float b[7]={0.f,0.f,0.f,0.f,0.f,0.f,0.f};
#pragma unroll
  for(int i=0;i<6;i++){
    float t=(el[i]-(float)rem0i[i])*down;
    int k0=5-rank[i]; if(k0>=0&&k0<7) b[k0]+=t;
  }
#pragma unroll
  for(int i=0;i<6;i++){
    float t=(el[i]-(float)rem0i[i])*down;
    int k1=6-rank[i]; if(k1>=0&&k1<7) b[k1]-=t;
  }
  baryT[n]=(b[0]+1.0f)+b[6];
#pragma unroll
  for(int r=1;r<6;r++) baryT[(size_t)r*N+n]=b[r];

#pragma unroll 1
  for(int r=0;r<6;r++){
    long long code=0;
#pragma unroll
    for(int i=0;i<5;i++){
      int key = rem0i[i] + ((rank[i] >= 6-r) ? (r-6) : r);
      code = code*2048 + (long long)(key+1024);
    }
    u32 h=(u32)mix64((u64)code)&cmask;
    u32 slot=0xFFFFFFFFu;
#pragma unroll 1
    for(int p=0;p<PROBE_CAP;p++){
      u64 cur=tabk[h];
      if(cur==(u64)code){ slot=h; break; }
      if(cur==KEMPTY){
        u64 old=atomicCAS((unsigned long long*)&tabk[h], KEMPTY, (u64)code);
        if(old==KEMPTY || old==(u64)code){ slot=h; break; }
      } else {
        h=(h+1)&cmask;
      }
    }
    inv_slot[(size_t)r*N+n]=slot;
  }
}

// ---------------- kernel 2: compact uids ----------------
__global__ void __launch_bounds__(256)
k_uid(const u64* __restrict__ tabk, u32 C, u32 Ucap, u32* __restrict__ tuid,
      u32* __restrict__ uidslot, u32* __restrict__ counter)
{
  u32 s=blockIdx.x*256+threadIdx.x;
  if(s>=C) return;
  if(tabk[s]==KEMPTY) return;
  u32 uid=atomicAdd(counter,1u);
  if(uid<Ucap) uidslot[uid]=s; else uid=0;
  tuid[s]=uid;
}

// ---------------- kernel 3: slot -> uid translation + u16 mirror ----------------
__global__ void __launch_bounds__(256)
k_translate(u32* __restrict__ inv, u16* __restrict__ inv16,
            const u32* __restrict__ tuid, size_t M)
{
  size_t i=(size_t)blockIdx.x*256+threadIdx.x;
  if(i<M){
    u32 u=tuid[inv[i]];
    inv[i]=u;
    inv16[i]=(u16)u;   // valid only when U<65536 (single-pass path gate U<=23040)
  }
}

// ---------------- values transpose: [N][16] -> valuesT[16][N] ----------------
__global__ void __launch_bounds__(256)
k_vtrans(const float* __restrict__ values, float* __restrict__ valuesT, int N)
{
  __shared__ float tile[256][17];
  u32 b=blockIdx.x, t=threadIdx.x;
  size_t p=(size_t)b*256+t;
  float v[16];
  row_load(values+p*16, v);
#pragma unroll
  for(int k=0;k<16;k++) tile[t][k]=v[k];
  __syncthreads();
  u32 ch=t>>4, lane=t&15;
#pragma unroll
  for(int q=0;q<16;q++){
    u32 pt=q*16+lane;
    valuesT[(size_t)ch*N + (size_t)b*256 + pt]=tile[pt][ch];
  }
}

// ================= SINGLE-PASS 1-CHANNEL SPLAT (U <= THRESH) =================
// 256 blocks (1/CU, 162.5KB static LDS, 16 waves). block j: cs=j&15, sub=j>>4.
// 4-point vectorized loads (ushort4/float4 per plane) + 2-way replicated
// accumulator (halves hot-vertex same-address serialization; replica offset
// 20320 is bank-aligned -> only a cheap 2-way bank alias per m136).
__global__ void __launch_bounds__(1024, 1)
k_saccum1(const u16* __restrict__ inv16, const float* __restrict__ baryT,
          const float* __restrict__ valuesT, const u32* __restrict__ counter,
          int N, float* __restrict__ partial1)
{
  __shared__ float acc1[2*R2CAP];   // 162560 B
  u32 U=*counter;
  if(U>THRESH) return;
  u32 j=blockIdx.x;
  u32 cs=j&15, sub=j>>4;
  u32 t=threadIdx.x;
  bool rep2 = (U<=R2CAP);

  if(rep2){ for(u32 x=t;x<2*R2CAP;x+=1024) acc1[x]=0.f; }
  else    { for(u32 x=t;x<U;x+=1024) acc1[x]=0.f; }
  __syncthreads();

  u32 nsub=(u32)N/S1;                 // 65536 points per block
  u32 quads=nsub>>2;                  // 16384
  size_t p0=(size_t)sub*nsub;
  const float* vch=valuesT+(size_t)cs*N;

  if(rep2){
    u32 rep=(t&1)*R2CAP;
    for(u32 q=t;q<quads;q+=1024){
      size_t p=p0+(size_t)q*4;
      float4 v=*(const float4*)(vch+p);
#pragma unroll
      for(int r=0;r<6;r++){
        ushort4 uu=*(const ushort4*)(inv16+(size_t)r*N+p);
        float4  w =*(const float4*)(baryT+(size_t)r*N+p);
        lds_add(&acc1[rep+uu.x], w.x*v.x);
        lds_add(&acc1[rep+uu.y], w.y*v.y);
        lds_add(&acc1[rep+uu.z], w.z*v.z);
        lds_add(&acc1[rep+uu.w], w.w*v.w);
      }
    }
  } else {
    for(u32 q=t;q<quads;q+=1024){
      size_t p=p0+(size_t)q*4;
      float4 v=*(const float4*)(vch+p);
#pragma unroll
      for(int r=0;r<6;r++){
        ushort4 uu=*(const ushort4*)(inv16+(size_t)r*N+p);
        float4  w =*(const float4*)(baryT+(size_t)r*N+p);
        lds_add(&acc1[uu.x], w.x*v.x);
        lds_add(&acc1[uu.y], w.y*v.y);
        lds_add(&acc1[uu.z], w.z*v.z);
        lds_add(&acc1[uu.w], w.w*v.w);
      }
    }
  }
  __syncthreads();
  float* dst=partial1+(size_t)j*UMAXR;
  if(rep2){ for(u32 x=t;x<U;x+=1024) dst[x]=acc1[x]+acc1[R2CAP+x]; }
  else    { for(u32 x=t;x<U;x+=1024) dst[x]=acc1[x]; }
}

// sum the 16 sub-partials of each channel into v0
__global__ void __launch_bounds__(256)
k_reduce1(const float* __restrict__ partial1, const u32* __restrict__ counter,
          float* __restrict__ v0)
{
  u32 U=*counter;
  if(U>THRESH) return;
  u32 cs=blockIdx.y;
  u32 u=blockIdx.x*256+threadIdx.x;
  if(u>=U) return;
  float s=0.f;
#pragma unroll
  for(u32 sub=0;sub<S1;sub++)
    s+=partial1[(size_t)(sub*16+cs)*UMAXR+u];
  v0[(size_t)u*16+cs]=s;
}

// ================= PARTITION PATH (U > THRESH) =================
__global__ void __launch_bounds__(256)
k_hist(const u32* __restrict__ inv, const u32* __restrict__ counter,
       u32* __restrict__ hist, size_t M)
{
  if(*counter<=THRESH) return;
  __shared__ u32 h[BINS];
  u32 t=threadIdx.x, b=blockIdx.x;
#pragma unroll
  for(int j=0;j<(int)(BINS/256);j++) h[t+j*256]=0;
  __syncthreads();
  size_t base=(size_t)b*CHUNK;
#pragma unroll
  for(int j=0;j<(int)(CHUNK/256);j++){
    size_t i=base + (size_t)j*256 + t;
    if(i<M){
      u32 u=inv[i];
      lds_addu(&h[u&(BINS-1)],1u);
    }
  }
  __syncthreads();
#pragma unroll
  for(int j=0;j<(int)(BINS/256);j++){
    u32 bin=t+j*256;
    hist[(size_t)b*BINS+bin]=h[bin];
  }
}

__global__ void __launch_bounds__(256)
k_transpose(const u32* __restrict__ in, u32* __restrict__ out, u32 R, u32 C,
            const u32* __restrict__ counter)
{
  if(*counter<=THRESH) return;
  __shared__ u32 tile[32][33];
  u32 bx=blockIdx.x, by=blockIdx.y;
  u32 tx=threadIdx.x&31, ty=threadIdx.x>>5;
  u32 c0=bx*32, r0=by*32;
#pragma unroll
  for(u32 j=0;j<32;j+=8){
    u32 r=r0+ty+j, c=c0+tx;
    if(r<R && c<C) tile[ty+j][tx]=in[(size_t)r*C+c];
  }
  __syncthreads();
#pragma unroll
  for(u32 j=0;j<32;j+=8){
    u32 c=c0+ty+j, r=r0+tx;
    if(c<C && r<R) out[(size_t)c*R+r]=tile[tx][ty+j];
  }
}

__global__ void __launch_bounds__(256)
k_scan1(const u32* __restrict__ v, u32* __restrict__ bsum, const u32* __restrict__ counter)
{
  if(*counter<=THRESH) return;
  __shared__ u32 sm[256];
  u32 t=threadIdx.x, b=blockIdx.x;
  size_t base=((size_t)b*256+t)*4;
  u32 s=v[base]+v[base+1]+v[base+2]+v[base+3];
  sm[t]=s; __syncthreads();
  for(int o=128;o>0;o>>=1){ if(t<(u32)o) sm[t]+=sm[t+o]; __syncthreads(); }
  if(t==0) bsum[b]=sm[0];
}

__global__ void __launch_bounds__(256)
k_scan2(u32* __restrict__ bsum, u32 nb, const u32* __restrict__ counter)
{
  if(*counter<=THRESH) return;
  __shared__ u32 sm[256];
  u32 t=threadIdx.x;
  u32 per=(nb+255)/256;
  u32 lo=t*per, hi=lo+per; if(hi>nb) hi=nb; if(lo>nb) lo=nb;
  u32 tot=0;
  for(u32 i=lo;i<hi;i++) tot+=bsum[i];
  sm[t]=tot; __syncthreads();
  for(int o=1;o<256;o<<=1){
    u32 v=sm[t]; u32 a=(t>=(u32)o)?sm[t-o]:0u; __syncthreads();
    sm[t]=v+a; __syncthreads();
  }
  u32 run=sm[t]-tot;
  for(u32 i=lo;i<hi;i++){ u32 c=bsum[i]; bsum[i]=run; run+=c; }
}

__global__ void __launch_bounds__(256)
k_scan3(u32* __restrict__ v, const u32* __restrict__ bsum, const u32* __restrict__ counter)
{
  if(*counter<=THRESH) return;
  __shared__ u32 sm[256];
  u32 t=threadIdx.x, b=blockIdx.x;
  size_t base=((size_t)b*256+t)*4;
  u32 c[4]; u32 tot=0;
#pragma unroll
  for(int j=0;j<4;j++){ c[j]=v[base+j]; tot+=c[j]; }
  sm[t]=tot; __syncthreads();
  for(int o=1;o<256;o<<=1){
    u32 x=sm[t]; u32 a=(t>=(u32)o)?sm[t-o]:0u; __syncthreads();
    sm[t]=x+a; __syncthreads();
  }
  u32 run=bsum[b]+sm[t]-tot;
#pragma unroll
  for(int j=0;j<4;j++){ v[base+j]=run; run+=c[j]; }
}

__global__ void __launch_bounds__(256)
k_part(const u32* __restrict__ inv, const float* __restrict__ baryT,
       const u32* __restrict__ histT, u32 nb,
       u32* __restrict__ skey, float* __restrict__ sw, size_t M, u32 nmask,
       const u32* __restrict__ counter)
{
  if(*counter<=THRESH) return;
  __shared__ u32 cur[BINS];
  u32 t=threadIdx.x, b=blockIdx.x;
#pragma unroll
  for(int j=0;j<(int)(BINS/256);j++){
    u32 bin=t+j*256;
    cur[bin]=histT[(size_t)bin*nb+b];
  }
  __syncthreads();
  size_t base=(size_t)b*CHUNK;
#pragma unroll
  for(int j=0;j<(int)(CHUNK/256);j++){
    size_t i=base+(size_t)j*256+t;
    if(i<M){
      u32 u=inv[i];
      u32 pos=lds_addu_rtn(&cur[u&(BINS-1)],1u);
      skey[pos]=((u>>12)<<20)|((u32)i & nmask);
      sw[pos]=baryT[i];
    }
  }
}

__global__ void __launch_bounds__(256)
k_queue(const u32* __restrict__ histT, u32 nb, size_t M,
        u32* __restrict__ q, u32* __restrict__ qn, const u32* __restrict__ counter)
{
  if(*counter<=THRESH) return;
  u32 b=blockIdx.x*256+threadIdx.x;
  if(b>=BINS) return;
  size_t s=histT[(size_t)b*nb];
  size_t e=(b+1<BINS)? (size_t)histT[(size_t)(b+1)*nb] : M;
  u32 sz=(u32)(e-s);
  if(sz==0) return;
  u32 G=(sz+SPLIT-1)/SPLIT; if(G>1023u) G=1023u;
  u32 base=atomicAdd(qn,G);
  for(u32 g=0; g<G; g++) q[base+g] = b | (g<<12) | (G<<22);
}

__global__ void __launch_bounds__(256)
k_accum(const u32* __restrict__ q, const u32* __restrict__ qn,
        const u32* __restrict__ skey, const float* __restrict__ sw,
        const float* __restrict__ values, const u32* __restrict__ histT,
        u32 nb, u32 rows, size_t M, float* __restrict__ v0)
{
  __shared__ float acc[4352];
  u32 j=blockIdx.x;
  if(j>=*qn) return;
  u32 ent=q[j];
  u32 b=ent&4095u, g=(ent>>12)&1023u, G=ent>>22;
  size_t s0=histT[(size_t)b*nb];
  size_t e0=(b+1<BINS)? (size_t)histT[(size_t)(b+1)*nb] : M;
  u32 sz=(u32)(e0-s0);
  u32 chunk=(sz+G-1)/G;
  size_t s=s0+(size_t)g*chunk;
  size_t e=s+chunk; if(e>e0) e=e0;

  u32 t=threadIdx.x;
  for(u32 x=t;x<rows*17;x+=256) acc[x]=0.f;
  __syncthreads();

  if(G==1){
    size_t base=s;
    for(; base+512<=e; base+=512){
      size_t i0=base+t, i1=base+256+t;
      u32 key0=skey[i0], key1=skey[i1];
      float w0=sw[i0], w1=sw[i1];
      float r0[16], r1[16];
      row_load(values+(size_t)(key0&0xFFFFFu)*16, r0);
      row_load(values+(size_t)(key1&0xFFFFFu)*16, r1);
      u32 a0=(key0>>20)*17, a1=(key1>>20)*17;
#pragma unroll
      for(int k=0;k<16;k++) lds_add(&acc[a0+k], w0*r0[k]);
#pragma unroll
      for(int k=0;k<16;k++) lds_add(&acc[a1+k], w1*r1[k]);
    }
    for(; base<e; base+=256){
      size_t ei=base+t;
      if(ei<e){
        u32 key=skey[ei]; float w=sw[ei];
        float r[16];
        row_load(values+(size_t)(key&0xFFFFFu)*16, r);
        u32 a=(key>>20)*17;
#pragma unroll
        for(int k=0;k<16;k++) lds_add(&acc[a+k], w*r[k]);
      }
    }
  } else {
    u32 gr=t>>4, k=t&15;
    size_t base=s;
    for(; base+128<=e; base+=128){
      u32 key[8]; float w[8]; float x[8];
#pragma unroll
      for(int u8=0;u8<8;u8++){ size_t ei=base+(size_t)u8*16+gr; key[u8]=skey[ei]; w[u8]=sw[ei]; }
#pragma unroll
      for(int u8=0;u8<8;u8++){ x[u8]=values[(size_t)(key[u8]&0xFFFFFu)*16+k]; }
#pragma unroll
      for(int u8=0;u8<8;u8++) lds_add(&acc[(key[u8]>>20)*17+k], w[u8]*x[u8]);
    }
    for(; base<e; base+=16){
      size_t ei=base+gr;
      if(ei<e){
        u32 key=skey[ei]; float w=sw[ei];
        float x=values[(size_t)(key&0xFFFFFu)*16+k];
        lds_add(&acc[(key>>20)*17+k], w*x);
      }
    }
  }
  __syncthreads();

  if(G==1){
    for(u32 x=t;x<rows*16;x+=256){
      u32 row=x>>4, kk=x&15;
      v0[(size_t)((row<<12)|b)*16+kk]=acc[row*17+kk];
    }
  } else {
    for(u32 x=t;x<rows*16;x+=256){
      u32 row=x>>4, kk=x&15;
      float a=acc[row*17+kk];
      if(a!=0.f) atomAddF(&v0[(size_t)((row<<12)|b)*16+kk], a);
    }
  }
}

// ---------------- blur ----------------
__global__ void __launch_bounds__(256)
k_blur(const u64* __restrict__ tabk, const u32* __restrict__ tuid, u32 cmask,
       const u32* __restrict__ uidslot, const u32* __restrict__ counter, u32 Ucap,
       long long delta, const float* __restrict__ vin, float* __restrict__ vout)
{
  u32 m=blockIdx.x*256+threadIdx.x;
  u32 U=*counter; if(U>Ucap) U=Ucap;
  if(m>=U) return;
  long long code=(long long)tabk[uidslot[m]];
  long long sp=lookup_slot(tabk,cmask,(u64)(code+delta));
  long long sm=lookup_slot(tabk,cmask,(u64)(code-delta));
  float acc[16];
  row_load(vin+(size_t)m*16, acc);
#pragma unroll
  for(int k=0;k<16;k++) acc[k]*=0.5f;
  if(sp>=0){
    u32 u=tuid[sp]; float t[16]; row_load(vin+(size_t)u*16,t);
#pragma unroll
    for(int k=0;k<16;k++) acc[k]+=0.25f*t[k];
  }
  if(sm>=0){
    u32 u=tuid[sm]; float t[16]; row_load(vin+(size_t)u*16,t);
#pragma unroll
    for(int k=0;k<16;k++) acc[k]+=0.25f*t[k];
  }
  row_store(vout+(size_t)m*16, acc);
}

// ---------------- slice (planar inv/bary) ----------------
__global__ void __launch_bounds__(256)
k_slice(const u32* __restrict__ inv, const float* __restrict__ baryT,
        const float* __restrict__ val, int N, float* __restrict__ out)
{
  int n=blockIdx.x*256+threadIdx.x;
  if(n>=N) return;
  u32 u[6]; float w[6];
#pragma unroll
  for(int r=0;r<6;r++){ u[r]=inv[(size_t)r*N+n]; w[r]=baryT[(size_t)r*N+n]; }
  float t6[6][16];
#pragma unroll
  for(int r=0;r<6;r++) row_load(val+(size_t)u[r]*16, t6[r]);
  float acc[16];
#pragma unroll
  for(int k=0;k<16;k++){
    float a=w[0]*t6[0][k];
#pragma unroll
    for(int r=1;r<6;r++) a+=w[r]*t6[r][k];
    acc[k]=a;
  }
  const float alpha=0.9696969696969697f;
  float4* q=(float4*)(out+(size_t)n*16);
#pragma unroll
  for(int i=0;i<4;i++) q[i]=make_float4(alpha*acc[4*i],alpha*acc[4*i+1],alpha*acc[4*i+2],alpha*acc[4*i+3]);
}

__global__ void k_diag(float* out, float v){ out[0]=v; }

// ---------------- host ----------------
extern "C" void kernel_launch(void* const* d_in, const int* in_sizes, int n_in,
                              void* d_out, int out_size, void* d_ws, size_t ws_size,
                              hipStream_t stream)
{
  const float* feat   =(const float*)d_in[0];
  const float* values =(const float*)d_in[1];
  float* out=(float*)d_out;
  int N=in_sizes[0]/5;          // 2^20
  size_t M=(size_t)N*6;
  u32 nmask=(u32)(N-1);

  u32 nb=(u32)((M+CHUNK-1)/CHUNK);
  size_t K=(size_t)nb*BINS;
  const u32 QCAP=16384;

  // v1 union: partition scratch OR (valuesT + partial1) OR blur pingpong
  size_t part_scratch = K*4+K*4+M*4+M*4+(K/1024)*4+QCAP*4+1024;
  size_t vt_bytes     = (size_t)N*16*4;                    // 67.1 MB
  size_t partial1b    = (size_t)256*UMAXR*4;               // 23.6 MB
  auto v1bytes=[&](size_t U)->size_t{
    size_t m1=U*64;
    if(part_scratch>m1) m1=part_scratch;
    if(vt_bytes+partial1b>m1) m1=vt_bytes+partial1b;
    return m1;
  };
  auto need=[&](int lC,int lU)->size_t{
    size_t C=1ull<<lC, U=1ull<<lU, s=0;
    auto al=[&](size_t b){ s=(s+255)&~(size_t)255; s+=b; };
    al(4); al(M*4); al(M*4); al(M*2); al(C*8); al(C*4); al(U*4); al(U*64); al(v1bytes(U));
    return s+256;
  };
  const int prefs[3][2]={{21,20},{21,19},{20,18}};
  int lC=0,lU=0;
  for(int i=0;i<3;i++){ if(need(prefs[i][0],prefs[i][1])<=ws_size){ lC=prefs[i][0]; lU=prefs[i][1]; break; } }
  if(!lC){
    hipMemsetAsync(d_out,0,(size_t)out_size*sizeof(float),stream);
    k_diag<<<1,1,0,stream>>>(out,(float)(ws_size>>20));
    return;
  }

  size_t C=1ull<<lC, Ucap=1ull<<lU; u32 cmask=(u32)(C-1);
  char* base=(char*)d_ws; size_t offb=0;
  auto carve=[&](size_t b)->char*{ offb=(offb+255)&~(size_t)255; char* p=base+offb; offb+=b; return p; };
  u32*   counter=(u32*)carve(4);
  u32*   inv    =(u32*)carve(M*4);
  float* baryT  =(float*)carve(M*4);
  u16*   inv16  =(u16*)carve(M*2);
  u64*   tabk   =(u64*)carve(C*8);
  u32*   tuid   =(u32*)carve(C*4);
  u32*   uidslot=(u32*)carve(Ucap*4);
  float* v0     =(float*)carve(Ucap*64);
  float* v1     =(float*)carve(v1bytes(Ucap));

  // partition aliases
  u32*   hist =(u32*)v1;
  u32*   histT=hist+K;
  u32*   skey =histT+K;
  float* sw   =(float*)(skey+M);
  u32*   bsum =(u32*)(sw+M);
  u32*   q    =bsum+(K/1024);
  u32*   qn   =q+QCAP;
  // single-pass aliases
  float* valuesT =(float*)v1;
  float* partial1=(float*)((char*)v1+vt_bytes);

  hipMemsetAsync(counter,0,4,stream);
  hipMemsetAsync(tabk,0xFF,C*8,stream);
  hipMemsetAsync(v0,0,Ucap*64,stream);

  const int B=256;
  k_setup    <<<(N+B-1)/B,B,0,stream>>>(feat,N,tabk,cmask,inv,baryT);
  k_uid      <<<(u32)((C+B-1)/B),B,0,stream>>>(tabk,(u32)C,(u32)Ucap,tuid,uidslot,counter);
  k_translate<<<(u32)((M+B-1)/B),B,0,stream>>>(inv,inv16,tuid,M);

  // ---- single-pass splat (dead unless U<=23040) ----
  k_vtrans <<<(u32)(N/256),B,0,stream>>>(values,valuesT,N);
  k_saccum1<<<16*S1,1024,0,stream>>>(inv16,baryT,valuesT,counter,N,partial1);
  {
    dim3 g((THRESH+B-1)/B,16);
    k_reduce1<<<g,B,0,stream>>>(partial1,counter,v0);
  }

  // ---- partition path (dead unless U > 23040) ----
  hipMemsetAsync(qn,0,4,stream);
  k_hist <<<nb,B,0,stream>>>(inv,counter,hist,M);
  {
    dim3 g((BINS+31)/32,(nb+31)/32);
    k_transpose<<<g,B,0,stream>>>(hist,histT,nb,BINS,counter);
  }
  u32 sb=(u32)(K/1024);
  k_scan1<<<sb,B,0,stream>>>(histT,bsum,counter);
  k_scan2<<<1 ,B,0,stream>>>(bsum,sb,counter);
  k_scan3<<<sb,B,0,stream>>>(histT,bsum,counter);
  k_part <<<nb,B,0,stream>>>(inv,baryT,histT,nb,skey,sw,M,nmask,counter);
  k_queue<<<(BINS+B-1)/B,B,0,stream>>>(histT,nb,M,q,qn,counter);
  u32 rows=(u32)(Ucap>>12);
  k_accum<<<QCAP,B,0,stream>>>(q,qn,skey,sw,values,histT,nb,rows,M,v0);

  const long long P[5]={1ll,2048ll,1ll<<22,1ll<<33,1ll<<44};
  const long long SUM=P[0]+P[1]+P[2]+P[3]+P[4];
  u32 gb=(u32)((Ucap+B-1)/B);
  float* a=v0; float* bb=v1;
  for(int j=0;j<6;j++){
    long long delta=(j<5)? (SUM-6*P[4-j]) : SUM;
    k_blur<<<gb,B,0,stream>>>(tabk,tuid,cmask,uidslot,counter,(u32)Ucap,delta,a,bb);
    float* t=a; a=bb; bb=t;
  }
  k_slice<<<(N+B-1)/B,B,0,stream>>>(inv,baryT,a,N,out);
}

// Round 17
// 1037.794 us; speedup vs baseline: 1.2176x; 1.0171x over previous
//
#include <hip/hip_runtime.h>
#include <stdint.h>

typedef unsigned long long u64;
typedef unsigned int u32;
typedef unsigned short u16;

static constexpr u64 KEMPTY = ~0ull;
static constexpr int PROBE_CAP = 32768;
static constexpr u32 BINS  = 4096;
static constexpr u32 CHUNK = 4096;
static constexpr u32 SPLIT = 2048;

static constexpr u32 THRESH = 23040;   // single-pass splat capacity == tier gate
static constexpr u32 UMAXR  = 23040;   // big-variant partial1 row stride
static constexpr u32 USM    = 12672;   // small-variant capacity (50688 B LDS -> 2 blocks/CU)

static __device__ __forceinline__ u64 mix64(u64 x){
  x ^= x >> 30; x *= 0xbf58476d1ce4e5b9ull;
  x ^= x >> 27; x *= 0x94d049bb133111ebull;
  x ^= x >> 31; return x;
}

static __device__ __forceinline__ long long lookup_slot(const u64* __restrict__ tk, u32 cmask, u64 code){
  u32 h = (u32)mix64(code) & cmask;
#pragma unroll 1
  for(int p=0;p<PROBE_CAP;p++){
    u64 cur = tk[h];
    if(cur==code) return (long long)h;
    if(cur==KEMPTY) return -1;
    h=(h+1)&cmask;
  }
  return -1;
}

static __device__ __forceinline__ void atomAddF(float* p, float v){
#if defined(__gfx90a__) || defined(__gfx940__) || defined(__gfx941__) || defined(__gfx942__) || defined(__gfx950__)
  unsafeAtomicAdd(p, v);
#else
  atomicAdd(p, v);
#endif
}

static __device__ __forceinline__ void lds_add(float* p, float v){
  __hip_atomic_fetch_add(p, v, __ATOMIC_RELAXED, __HIP_MEMORY_SCOPE_WORKGROUP);
}
static __device__ __forceinline__ void lds_addu(u32* p, u32 v){
  __hip_atomic_fetch_add(p, v, __ATOMIC_RELAXED, __HIP_MEMORY_SCOPE_WORKGROUP);
}
static __device__ __forceinline__ u32 lds_addu_rtn(u32* p, u32 v){
  return __hip_atomic_fetch_add(p, v, __ATOMIC_RELAXED, __HIP_MEMORY_SCOPE_WORKGROUP);
}

static __device__ __forceinline__ void row_load(const float* __restrict__ p, float* o){
  const float4* q=(const float4*)p;
#pragma unroll
  for(int i=0;i<4;i++){ float4 v=q[i]; o[4*i]=v.x; o[4*i+1]=v.y; o[4*i+2]=v.z; o[4*i+3]=v.w; }
}
static __device__ __forceinline__ void row_store(float* __restrict__ p, const float* o){
  float4* q=(float4*)p;
#pragma unroll
  for(int i=0;i<4;i++) q[i]=make_float4(o[4*i],o[4*i+1],o[4*i+2],o[4*i+3]);
}

// ---------------- kernel 1: elevate/rank/bary + table insert (PLANAR outputs) ----------------
__global__ void __launch_bounds__(256)
k_setup(const float* __restrict__ feat, int N,
        u64* __restrict__ tabk, u32 cmask,
        u32* __restrict__ inv_slot, float* __restrict__ baryT)
{
#pragma clang fp contract(off)
  int n = blockIdx.x*256 + threadIdx.x;
  if(n>=N) return;

  const float s0=3.4641016151377544f, s1=2.0f, s2=1.4142135623730951f,
              s3=1.0954451150103321f, s4=0.8944271909999159f;
  float c[5];
  c[0]=feat[n*5+0]*s0; c[1]=feat[n*5+1]*s1; c[2]=feat[n*5+2]*s2;
  c[3]=feat[n*5+3]*s3; c[4]=feat[n*5+4]*s4;

  float sfx[6]; sfx[5]=0.f;
#pragma unroll
  for(int i=4;i>=0;i--) sfx[i]=sfx[i+1]+c[i];
  float el[6];
  el[0]=sfx[0];
#pragma unroll
  for(int i=1;i<6;i++) el[i]=sfx[i]-(float)i*c[i-1];

  const float down=1.0f/6.0f;
  float rd[6], rem0[6], rdsum=0.f;
#pragma unroll
  for(int i=0;i<6;i++){ rd[i]=rintf(el[i]*down); rem0[i]=rd[i]*6.0f; rdsum+=rd[i]; }
  int sumi=(int)rdsum;

  float diff[6];
#pragma unroll
  for(int i=0;i<6;i++) diff[i]=(el[i]-rem0[i])*down;

  int rank[6];
#pragma unroll
  for(int i=0;i<6;i++){
    int r=0;
#pragma unroll
    for(int j=0;j<6;j++)
      r += (diff[j]>diff[i]) || (diff[j]==diff[i] && j<i);
    rank[i]=r+sumi;
  }
  int rem0i[6];
#pragma unroll
  for(int i=0;i<6;i++){
    rem0i[i]=(int)rem0[i];
    int sh=(rank[i]<0)-(rank[i]>5);
    rank[i]+=6*sh; rem0i[i]+=6*sh;
  }

  float b[7]={0.f,0.f,0.f,0.f,0.f,0.f,0.f};
#pragma unroll
  for(int i=0;i<6;i++){
    float t=(el[i]-(float)rem0i[i])*down;
    int k0=5-rank[i]; if(k0>=0&&k0<7) b[k0]+=t;
  }
#pragma unroll
  for(int i=0;i<6;i++){
    float t=(el[i]-(float)rem0i[i])*down;
    int k1=6-rank[i]; if(k1>=0&&k1<7) b[k1]-=t;
  }
  baryT[n]=(b[0]+1.0f)+b[6];
#pragma unroll
  for(int r=1;r<6;r++) baryT[(size_t)r*N+n]=b[r];

#pragma unroll 1
  for(int r=0;r<6;r++){
    long long code=0;
#pragma unroll
    for(int i=0;i<5;i++){
      int key = rem0i[i] + ((rank[i] >= 6-r) ? (r-6) : r);
      code = code*2048 + (long long)(key+1024);
    }
    u32 h=(u32)mix64((u64)code)&cmask;
    u32 slot=0xFFFFFFFFu;
#pragma unroll 1
    for(int p=0;p<PROBE_CAP;p++){
      u64 cur=tabk[h];
      if(cur==(u64)code){ slot=h; break; }
      if(cur==KEMPTY){
        u64 old=atomicCAS((unsigned long long*)&tabk[h], KEMPTY, (u64)code);
        if(old==KEMPTY || old==(u64)code){ slot=h; break; }
      } else {
        h=(h+1)&cmask;
      }
    }
    inv_slot[(size_t)r*N+n]=slot;
  }
}

// ---------------- kernel 2: compact uids ----------------
__global__ void __launch_bounds__(256)
k_uid(const u64* __restrict__ tabk, u32 C, u32 Ucap, u32* __restrict__ tuid,
      u32* __restrict__ uidslot, u32* __restrict__ counter)
{
  u32 s=blockIdx.x*256+threadIdx.x;
  if(s>=C) return;
  if(tabk[s]==KEMPTY) return;
  u32 uid=atomicAdd(counter,1u);
  if(uid<Ucap) uidslot[uid]=s; else uid=0;
  tuid[s]=uid;
}

// ---------------- kernel 3: slot -> uid translation + u16 mirror ----------------
__global__ void __launch_bounds__(256)
k_translate(u32* __restrict__ inv, u16* __restrict__ inv16,
            const u32* __restrict__ tuid, size_t M)
{
  size_t i=(size_t)blockIdx.x*256+threadIdx.x;
  if(i<M){
    u32 u=tuid[inv[i]];
    inv[i]=u;
    inv16[i]=(u16)u;   // valid only when U<65536 (single-pass path gate U<=23040)
  }
}

// ---------------- values transpose: [N][16] -> valuesT[16][N] ----------------
__global__ void __launch_bounds__(256)
k_vtrans(const float* __restrict__ values, float* __restrict__ valuesT, int N)
{
  __shared__ float tile[256][17];
  u32 b=blockIdx.x, t=threadIdx.x;
  size_t p=(size_t)b*256+t;
  float v[16];
  row_load(values+p*16, v);
#pragma unroll
  for(int k=0;k<16;k++) tile[t][k]=v[k];
  __syncthreads();
  u32 ch=t>>4, lane=t&15;
#pragma unroll
  for(int q=0;q<16;q++){
    u32 pt=q*16+lane;
    valuesT[(size_t)ch*N + (size_t)b*256 + pt]=tile[pt][ch];
  }
}

// ================= SPLAT VARIANT S: U <= USM, 2 blocks/CU (32 waves/CU) =================
__global__ void __launch_bounds__(1024, 8)
k_saccum1s(const u16* __restrict__ inv16, const float* __restrict__ baryT,
           const float* __restrict__ valuesT, const u32* __restrict__ counter,
           int N, float* __restrict__ partial1)
{
  __shared__ float acc1[USM];   // 50688 B
  u32 U=*counter;
  if(U>USM) return;
  u32 j=blockIdx.x;             // 512 blocks
  u32 cs=j&15, sub=j>>4;        // sub in [0,32)
  u32 t=threadIdx.x;
  for(u32 x=t;x<U;x+=1024) acc1[x]=0.f;
  __syncthreads();

  u32 nsub=(u32)N/32;           // 32768
  u32 quads=nsub>>2;            // 8192 -> 8 iters/thread
  size_t p0=(size_t)sub*nsub;
  const float* vch=valuesT+(size_t)cs*N;
  for(u32 q=t;q<quads;q+=1024){
    size_t p=p0+(size_t)q*4;
    float4 v=*(const float4*)(vch+p);
#pragma unroll
    for(int r=0;r<6;r++){
      ushort4 uu=*(const ushort4*)(inv16+(size_t)r*N+p);
      float4  w =*(const float4*)(baryT+(size_t)r*N+p);
      lds_add(&acc1[uu.x], w.x*v.x);
      lds_add(&acc1[uu.y], w.y*v.y);
      lds_add(&acc1[uu.z], w.z*v.z);
      lds_add(&acc1[uu.w], w.w*v.w);
    }
  }
  __syncthreads();
  float* dst=partial1+(size_t)j*USM;
  for(u32 x=t;x<U;x+=1024) dst[x]=acc1[x];
}

// ================= SPLAT VARIANT B: USM < U <= THRESH, software-pipelined =================
__global__ void __launch_bounds__(1024, 4)
k_saccum1b(const u16* __restrict__ inv16, const float* __restrict__ baryT,
           const float* __restrict__ valuesT, const u32* __restrict__ counter,
           int N, float* __restrict__ partial1)
{
  __shared__ float acc1[THRESH];   // 92160 B
  u32 U=*counter;
  if(U<=USM || U>THRESH) return;
  u32 j=blockIdx.x;                // 256 blocks
  u32 cs=j&15, sub=j>>4;           // sub in [0,16)
  u32 t=threadIdx.x;
  for(u32 x=t;x<U;x+=1024) acc1[x]=0.f;
  __syncthreads();

  u32 nsub=(u32)N/16;              // 65536
  u32 pairs=nsub>>1;               // 32768
  u32 iters=pairs/1024;            // 32
  size_t p0=(size_t)sub*nsub;
  const float* vch=valuesT+(size_t)cs*N;

  u32 q=t;
  float2 vA=make_float2(0.f,0.f); ushort2 uA[6]; float2 wA[6];
  {
    size_t p=p0+(size_t)q*2;
    vA=*(const float2*)(vch+p);
#pragma unroll
    for(int r=0;r<6;r++){
      uA[r]=*(const ushort2*)(inv16+(size_t)r*N+p);
      wA[r]=*(const float2*)(baryT+(size_t)r*N+p);
    }
  }
  for(u32 it=0;it<iters;++it){
    u32 qn2=q+1024;
    float2 vB=make_float2(0.f,0.f); ushort2 uB[6]; float2 wB[6];
#pragma unroll
    for(int r=0;r<6;r++){ uB[r]=make_ushort2(0,0); wB[r]=make_float2(0.f,0.f); }
    if(it+1<iters){
      size_t pn=p0+(size_t)qn2*2;
      vB=*(const float2*)(vch+pn);
#pragma unroll
      for(int r=0;r<6;r++){
        uB[r]=*(const ushort2*)(inv16+(size_t)r*N+pn);
        wB[r]=*(const float2*)(baryT+(size_t)r*N+pn);
      }
    }
#pragma unroll
    for(int r=0;r<6;r++){
      lds_add(&acc1[uA[r].x], wA[r].x*vA.x);
      lds_add(&acc1[uA[r].y], wA[r].y*vA.y);
    }
    vA=vB;
#pragma unroll
    for(int r=0;r<6;r++){ uA[r]=uB[r]; wA[r]=wB[r]; }
    q=qn2;
  }
  __syncthreads();
  float* dst=partial1+(size_t)j*UMAXR;
  for(u32 x=t;x<U;x+=1024) dst[x]=acc1[x];
}

// sum sub-partials of each channel into v0 (handles both variants)
__global__ void __launch_bounds__(256)
k_reduce1(const float* __restrict__ partial1, const u32* __restrict__ counter,
          float* __restrict__ v0)
{
  u32 U=*counter;
  if(U>THRESH) return;
  bool small=(U<=USM);
  u32 S = small?32u:16u;
  size_t stride = small?(size_t)USM:(size_t)UMAXR;
  u32 cs=blockIdx.y;
  u32 u=blockIdx.x*256+threadIdx.x;
  if(u>=U) return;
  float s=0.f;
  for(u32 sub=0;sub<S;sub++)
    s+=partial1[(size_t)(sub*16+cs)*stride+u];
  v0[(size_t)u*16+cs]=s;
}

// ================= PARTITION PATH (U > THRESH) =================
__global__ void __launch_bounds__(256)
k_hist(const u32* __restrict__ inv, const u32* __restrict__ counter,
       u32* __restrict__ hist, size_t M)
{
  if(*counter<=THRESH) return;
  __shared__ u32 h[BINS];
  u32 t=threadIdx.x, b=blockIdx.x;
#pragma unroll
  for(int j=0;j<(int)(BINS/256);j++) h[t+j*256]=0;
  __syncthreads();
  size_t base=(size_t)b*CHUNK;
#pragma unroll
  for(int j=0;j<(int)(CHUNK/256);j++){
    size_t i=base + (size_t)j*256 + t;
    if(i<M){
      u32 u=inv[i];
      lds_addu(&h[u&(BINS-1)],1u);
    }
  }
  __syncthreads();
#pragma unroll
  for(int j=0;j<(int)(BINS/256);j++){
    u32 bin=t+j*256;
    hist[(size_t)b*BINS+bin]=h[bin];
  }
}

__global__ void __launch_bounds__(256)
k_transpose(const u32* __restrict__ in, u32* __restrict__ out, u32 R, u32 C,
            const u32* __restrict__ counter)
{
  if(*counter<=THRESH) return;
  __shared__ u32 tile[32][33];
  u32 bx=blockIdx.x, by=blockIdx.y;
  u32 tx=threadIdx.x&31, ty=threadIdx.x>>5;
  u32 c0=bx*32, r0=by*32;
#pragma unroll
  for(u32 j=0;j<32;j+=8){
    u32 r=r0+ty+j, c=c0+tx;
    if(r<R && c<C) tile[ty+j][tx]=in[(size_t)r*C+c];
  }
  __syncthreads();
#pragma unroll
  for(u32 j=0;j<32;j+=8){
    u32 c=c0+ty+j, r=r0+tx;
    if(c<C && r<R) out[(size_t)c*R+r]=tile[tx][ty+j];
  }
}

__global__ void __launch_bounds__(256)
k_scan1(const u32* __restrict__ v, u32* __restrict__ bsum, const u32* __restrict__ counter)
{
  if(*counter<=THRESH) return;
  __shared__ u32 sm[256];
  u32 t=threadIdx.x, b=blockIdx.x;
  size_t base=((size_t)b*256+t)*4;
  u32 s=v[base]+v[base+1]+v[base+2]+v[base+3];
  sm[t]=s; __syncthreads();
  for(int o=128;o>0;o>>=1){ if(t<(u32)o) sm[t]+=sm[t+o]; __syncthreads(); }
  if(t==0) bsum[b]=sm[0];
}

__global__ void __launch_bounds__(256)
k_scan2(u32* __restrict__ bsum, u32 nb, const u32* __restrict__ counter)
{
  if(*counter<=THRESH) return;
  __shared__ u32 sm[256];
  u32 t=threadIdx.x;
  u32 per=(nb+255)/256;
  u32 lo=t*per, hi=lo+per; if(hi>nb) hi=nb; if(lo>nb) lo=nb;
  u32 tot=0;
  for(u32 i=lo;i<hi;i++) tot+=bsum[i];
  sm[t]=tot; __syncthreads();
  for(int o=1;o<256;o<<=1){
    u32 v=sm[t]; u32 a=(t>=(u32)o)?sm[t-o]:0u; __syncthreads();
    sm[t]=v+a; __syncthreads();
  }
  u32 run=sm[t]-tot;
  for(u32 i=lo;i<hi;i++){ u32 c=bsum[i]; bsum[i]=run; run+=c; }
}

__global__ void __launch_bounds__(256)
k_scan3(u32* __restrict__ v, const u32* __restrict__ bsum, const u32* __restrict__ counter)
{
  if(*counter<=THRESH) return;
  __shared__ u32 sm[256];
  u32 t=threadIdx.x, b=blockIdx.x;
  size_t base=((size_t)b*256+t)*4;
  u32 c[4]; u32 tot=0;
#pragma unroll
  for(int j=0;j<4;j++){ c[j]=v[base+j]; tot+=c[j]; }
  sm[t]=tot; __syncthreads();
  for(int o=1;o<256;o<<=1){
    u32 x=sm[t]; u32 a=(t>=(u32)o)?sm[t-o]:0u; __syncthreads();
    sm[t]=x+a; __syncthreads();
  }
  u32 run=bsum[b]+sm[t]-tot;
#pragma unroll
  for(int j=0;j<4;j++){ v[base+j]=run; run+=c[j]; }
}

__global__ void __launch_bounds__(256)
k_part(const u32* __restrict__ inv, const float* __restrict__ baryT,
       const u32* __restrict__ histT, u32 nb,
       u32* __restrict__ skey, float* __restrict__ sw, size_t M, u32 nmask,
       const u32* __restrict__ counter)
{
  if(*counter<=THRESH) return;
  __shared__ u32 cur[BINS];
  u32 t=threadIdx.x, b=blockIdx.x;
#pragma unroll
  for(int j=0;j<(int)(BINS/256);j++){
    u32 bin=t+j*256;
    cur[bin]=histT[(size_t)bin*nb+b];
  }
  __syncthreads();
  size_t base=(size_t)b*CHUNK;
#pragma unroll
  for(int j=0;j<(int)(CHUNK/256);j++){
    size_t i=base+(size_t)j*256+t;
    if(i<M){
      u32 u=inv[i];
      u32 pos=lds_addu_rtn(&cur[u&(BINS-1)],1u);
      skey[pos]=((u>>12)<<20)|((u32)i & nmask);
      sw[pos]=baryT[i];
    }
  }
}

__global__ void __launch_bounds__(256)
k_queue(const u32* __restrict__ histT, u32 nb, size_t M,
        u32* __restrict__ q, u32* __restrict__ qn, const u32* __restrict__ counter)
{
  if(*counter<=THRESH) return;
  u32 b=blockIdx.x*256+threadIdx.x;
  if(b>=BINS) return;
  size_t s=histT[(size_t)b*nb];
  size_t e=(b+1<BINS)? (size_t)histT[(size_t)(b+1)*nb] : M;
  u32 sz=(u32)(e-s);
  if(sz==0) return;
  u32 G=(sz+SPLIT-1)/SPLIT; if(G>1023u) G=1023u;
  u32 base=atomicAdd(qn,G);
  for(u32 g=0; g<G; g++) q[base+g] = b | (g<<12) | (G<<22);
}

__global__ void __launch_bounds__(256)
k_accum(const u32* __restrict__ q, const u32* __restrict__ qn,
        const u32* __restrict__ skey, const float* __restrict__ sw,
        const float* __restrict__ values, const u32* __restrict__ histT,
        u32 nb, u32 rows, size_t M, float* __restrict__ v0)
{
  __shared__ float acc[4352];
  u32 j=blockIdx.x;
  if(j>=*qn) return;
  u32 ent=q[j];
  u32 b=ent&4095u, g=(ent>>12)&1023u, G=ent>>22;
  size_t s0=histT[(size_t)b*nb];
  size_t e0=(b+1<BINS)? (size_t)histT[(size_t)(b+1)*nb] : M;
  u32 sz=(u32)(e0-s0);
  u32 chunk=(sz+G-1)/G;
  size_t s=s0+(size_t)g*chunk;
  size_t e=s+chunk; if(e>e0) e=e0;

  u32 t=threadIdx.x;
  for(u32 x=t;x<rows*17;x+=256) acc[x]=0.f;
  __syncthreads();

  if(G==1){
    size_t base=s;
    for(; base+512<=e; base+=512){
      size_t i0=base+t, i1=base+256+t;
      u32 key0=skey[i0], key1=skey[i1];
      float w0=sw[i0], w1=sw[i1];
      float r0[16], r1[16];
      row_load(values+(size_t)(key0&0xFFFFFu)*16, r0);
      row_load(values+(size_t)(key1&0xFFFFFu)*16, r1);
      u32 a0=(key0>>20)*17, a1=(key1>>20)*17;
#pragma unroll
      for(int k=0;k<16;k++) lds_add(&acc[a0+k], w0*r0[k]);
#pragma unroll
      for(int k=0;k<16;k++) lds_add(&acc[a1+k], w1*r1[k]);
    }
    for(; base<e; base+=256){
      size_t ei=base+t;
      if(ei<e){
        u32 key=skey[ei]; float w=sw[ei];
        float r[16];
        row_load(values+(size_t)(key&0xFFFFFu)*16, r);
        u32 a=(key>>20)*17;
#pragma unroll
        for(int k=0;k<16;k++) lds_add(&acc[a+k], w*r[k]);
      }
    }
  } else {
    u32 gr=t>>4, k=t&15;
    size_t base=s;
    for(; base+128<=e; base+=128){
      u32 key[8]; float w[8]; float x[8];
#pragma unroll
      for(int u8=0;u8<8;u8++){ size_t ei=base+(size_t)u8*16+gr; key[u8]=skey[ei]; w[u8]=sw[ei]; }
#pragma unroll
      for(int u8=0;u8<8;u8++){ x[u8]=values[(size_t)(key[u8]&0xFFFFFu)*16+k]; }
#pragma unroll
      for(int u8=0;u8<8;u8++) lds_add(&acc[(key[u8]>>20)*17+k], w[u8]*x[u8]);
    }
    for(; base<e; base+=16){
      size_t ei=base+gr;
      if(ei<e){
        u32 key=skey[ei]; float w=sw[ei];
        float x=values[(size_t)(key&0xFFFFFu)*16+k];
        lds_add(&acc[(key>>20)*17+k], w*x);
      }
    }
  }
  __syncthreads();

  if(G==1){
    for(u32 x=t;x<rows*16;x+=256){
      u32 row=x>>4, kk=x&15;
      v0[(size_t)((row<<12)|b)*16+kk]=acc[row*17+kk];
    }
  } else {
    for(u32 x=t;x<rows*16;x+=256){
      u32 row=x>>4, kk=x&15;
      float a=acc[row*17+kk];
      if(a!=0.f) atomAddF(&v0[(size_t)((row<<12)|b)*16+kk], a);
    }
  }
}

// ---------------- blur ----------------
__global__ void __launch_bounds__(256)
k_blur(const u64* __restrict__ tabk, const u32* __restrict__ tuid, u32 cmask,
       const u32* __restrict__ uidslot, const u32* __restrict__ counter, u32 Ucap,
       long long delta, const float* __restrict__ vin, float* __restrict__ vout)
{
  u32 m=blockIdx.x*256+threadIdx.x;
  u32 U=*counter; if(U>Ucap) U=Ucap;
  if(m>=U) return;
  long long code=(long long)tabk[uidslot[m]];
  long long sp=lookup_slot(tabk,cmask,(u64)(code+delta));
  long long sm=lookup_slot(tabk,cmask,(u64)(code-delta));
  float acc[16];
  row_load(vin+(size_t)m*16, acc);
#pragma unroll
  for(int k=0;k<16;k++) acc[k]*=0.5f;
  if(sp>=0){
    u32 u=tuid[sp]; float t[16]; row_load(vin+(size_t)u*16,t);
#pragma unroll
    for(int k=0;k<16;k++) acc[k]+=0.25f*t[k];
  }
  if(sm>=0){
    u32 u=tuid[sm]; float t[16]; row_load(vin+(size_t)u*16,t);
#pragma unroll
    for(int k=0;k<16;k++) acc[k]+=0.25f*t[k];
  }
  row_store(vout+(size_t)m*16, acc);
}

// ---------------- slice (planar inv/bary) ----------------
__global__ void __launch_bounds__(256)
k_slice(const u32* __restrict__ inv, const float* __restrict__ baryT,
        const float* __restrict__ val, int N, float* __restrict__ out)
{
  int n=blockIdx.x*256+threadIdx.x;
  if(n>=N) return;
  u32 u[6]; float w[6];
#pragma unroll
  for(int r=0;r<6;r++){ u[r]=inv[(size_t)r*N+n]; w[r]=baryT[(size_t)r*N+n]; }
  float t6[6][16];
#pragma unroll
  for(int r=0;r<6;r++) row_load(val+(size_t)u[r]*16, t6[r]);
  float acc[16];
#pragma unroll
  for(int k=0;k<16;k++){
    float a=w[0]*t6[0][k];
#pragma unroll
    for(int r=1;r<6;r++) a+=w[r]*t6[r][k];
    acc[k]=a;
  }
  const float alpha=0.9696969696969697f;
  float4* q=(float4*)(out+(size_t)n*16);
#pragma unroll
  for(int i=0;i<4;i++) q[i]=make_float4(alpha*acc[4*i],alpha*acc[4*i+1],alpha*acc[4*i+2],alpha*acc[4*i+3]);
}

__global__ void k_diag(float* out, float v){ out[0]=v; }

// ---------------- host ----------------
extern "C" void kernel_launch(void* const* d_in, const int* in_sizes, int n_in,
                              void* d_out, int out_size, void* d_ws, size_t ws_size,
                              hipStream_t stream)
{
  const float* feat   =(const float*)d_in[0];
  const float* values =(const float*)d_in[1];
  float* out=(float*)d_out;
  int N=in_sizes[0]/5;          // 2^20
  size_t M=(size_t)N*6;
  u32 nmask=(u32)(N-1);

  u32 nb=(u32)((M+CHUNK-1)/CHUNK);
  size_t K=(size_t)nb*BINS;
  const u32 QCAP=16384;

  // v1 union: partition scratch OR (valuesT + partial1) OR blur pingpong
  size_t part_scratch = K*4+K*4+M*4+M*4+(K/1024)*4+QCAP*4+1024;
  size_t vt_bytes     = (size_t)N*16*4;                       // 67.1 MB
  size_t partial1b    = (size_t)512*USM*4;                    // 25.95 MB (>= 256*UMAXR*4)
  if((size_t)256*UMAXR*4>partial1b) partial1b=(size_t)256*UMAXR*4;
  auto v1bytes=[&](size_t U)->size_t{
    size_t m1=U*64;
    if(part_scratch>m1) m1=part_scratch;
    if(vt_bytes+partial1b>m1) m1=vt_bytes+partial1b;
    return m1;
  };
  auto need=[&](int lC,int lU)->size_t{
    size_t C=1ull<<lC, U=1ull<<lU, s=0;
    auto al=[&](size_t b){ s=(s+255)&~(size_t)255; s+=b; };
    al(4); al(M*4); al(M*4); al(M*2); al(C*8); al(C*4); al(U*4); al(U*64); al(v1bytes(U));
    return s+256;
  };
  const int prefs[3][2]={{20,20},{20,19},{19,18}};
  int lC=0,lU=0;
  for(int i=0;i<3;i++){ if(need(prefs[i][0],prefs[i][1])<=ws_size){ lC=prefs[i][0]; lU=prefs[i][1]; break; } }
  if(!lC){
    hipMemsetAsync(d_out,0,(size_t)out_size*sizeof(float),stream);
    k_diag<<<1,1,0,stream>>>(out,(float)(ws_size>>20));
    return;
  }

  size_t C=1ull<<lC, Ucap=1ull<<lU; u32 cmask=(u32)(C-1);
  char* base=(char*)d_ws; size_t offb=0;
  auto carve=[&](size_t b)->char*{ offb=(offb+255)&~(size_t)255; char* p=base+offb; offb+=b; return p; };
  u32*   counter=(u32*)carve(4);
  u32*   inv    =(u32*)carve(M*4);
  float* baryT  =(float*)carve(M*4);
  u16*   inv16  =(u16*)carve(M*2);
  u64*   tabk   =(u64*)carve(C*8);
  u32*   tuid   =(u32*)carve(C*4);
  u32*   uidslot=(u32*)carve(Ucap*4);
  float* v0     =(float*)carve(Ucap*64);
  float* v1     =(float*)carve(v1bytes(Ucap));

  // partition aliases
  u32*   hist =(u32*)v1;
  u32*   histT=hist+K;
  u32*   skey =histT+K;
  float* sw   =(float*)(skey+M);
  u32*   bsum =(u32*)(sw+M);
  u32*   q    =bsum+(K/1024);
  u32*   qn   =q+QCAP;
  // single-pass aliases
  float* valuesT =(float*)v1;
  float* partial1=(float*)((char*)v1+vt_bytes);

  hipMemsetAsync(counter,0,4,stream);
  hipMemsetAsync(tabk,0xFF,C*8,stream);
  hipMemsetAsync(v0,0,Ucap*64,stream);

  const int B=256;
  k_setup    <<<(N+B-1)/B,B,0,stream>>>(feat,N,tabk,cmask,inv,baryT);
  k_uid      <<<(u32)((C+B-1)/B),B,0,stream>>>(tabk,(u32)C,(u32)Ucap,tuid,uidslot,counter);
  k_translate<<<(u32)((M+B-1)/B),B,0,stream>>>(inv,inv16,tuid,M);

  // ---- single-pass splat: two device-gated variants ----
  k_vtrans  <<<(u32)(N/256),B,0,stream>>>(values,valuesT,N);
  k_saccum1s<<<512,1024,0,stream>>>(inv16,baryT,valuesT,counter,N,partial1);
  k_saccum1b<<<256,1024,0,stream>>>(inv16,baryT,valuesT,counter,N,partial1);
  {
    dim3 g((THRESH+B-1)/B,16);
    k_reduce1<<<g,B,0,stream>>>(partial1,counter,v0);
  }

  // ---- partition path (dead unless U > 23040) ----
  hipMemsetAsync(qn,0,4,stream);
  k_hist <<<nb,B,0,stream>>>(inv,counter,hist,M);
  {
    dim3 g((BINS+31)/32,(nb+31)/32);
    k_transpose<<<g,B,0,stream>>>(hist,histT,nb,BINS,counter);
  }
  u32 sb=(u32)(K/1024);
  k_scan1<<<sb,B,0,stream>>>(histT,bsum,counter);
  k_scan2<<<1 ,B,0,stream>>>(bsum,sb,counter);
  k_scan3<<<sb,B,0,stream>>>(histT,bsum,counter);
  k_part <<<nb,B,0,stream>>>(inv,baryT,histT,nb,skey,sw,M,nmask,counter);
  k_queue<<<(BINS+B-1)/B,B,0,stream>>>(histT,nb,M,q,qn,counter);
  u32 rows=(u32)(Ucap>>12);
  k_accum<<<QCAP,B,0,stream>>>(q,qn,skey,sw,values,histT,nb,rows,M,v0);

  const long long P[5]={1ll,2048ll,1ll<<22,1ll<<33,1ll<<44};
  const long long SUM=P[0]+P[1]+P[2]+P[3]+P[4];
  u32 gb=(u32)((Ucap+B-1)/B);
  float* a=v0; float* bb=v1;
  for(int j=0;j<6;j++){
    long long delta=(j<5)? (SUM-6*P[4-j]) : SUM;
    k_blur<<<gb,B,0,stream>>>(tabk,tuid,cmask,uidslot,counter,(u32)Ucap,delta,a,bb);
    float* t=a; a=bb; bb=t;
  }
  k_slice<<<(N+B-1)/B,B,0,stream>>>(inv,baryT,a,N,out);
}